// Round 1
// baseline (1058.959 us; speedup 1.0000x reference)
//
#include <hip/hip_runtime.h>

// ---------------------------------------------------------------------------
// TransformerBlock: B=2,S=2048,D=2048,H=32,HD=64,G=8,KV=256,DFF=5632
// fp32 in/out. bf16 MFMA GEMMs (global_load_lds staging + XCD-locality block
// swizzle) + transposed-S flash attention (no P round-trip through LDS).
// R1: GEMM K-step widened 32->64 (m97 structure: 32 MFMA + 8 glds per barrier
// pair, 32KiB LDS) — amortizes the syncthreads vmcnt/lgkmcnt drain 2x.
// ---------------------------------------------------------------------------

typedef __attribute__((ext_vector_type(8))) __bf16 bf16x8;
typedef __attribute__((ext_vector_type(4))) __bf16 bf16x4;
typedef __attribute__((ext_vector_type(4))) float f32x4;

#define RR 4096      // B*S rows
#define DD 2048
#define KVD 256
#define QKVN 2560    // 2048 q + 256 k + 256 v
#define DFF 5632

// ---------------- workspace layout (bytes) ----------------
static const size_t OFF_WQKV = 0;              // bf16 [2560,2048]
static const size_t OFF_WO   = 10485760;       // bf16 [2048,2048]
static const size_t OFF_WG   = 18874368;       // bf16 [5632,2048]
static const size_t OFF_WU   = 41943040;       // bf16 [5632,2048]
static const size_t OFF_WDN  = 65011712;       // bf16 [2048,5632]
static const size_t OFF_H    = 88080384;       // bf16 [4096,2048]  (h, then attn_out)
static const size_t OFF_QKV  = 104857600;      // bf16 [4096,2560]
static const size_t OFF_Q    = 125829120;      // bf16 [4096,2048]  (q_rope, then h2)
static const size_t OFF_K    = 142606336;      // bf16 [4096,256]
static const size_t OFF_ACT  = 144703488;      // bf16 [4096,5632]  (gate tmp, then silu*up)
static const size_t WS_NEED  = 190840832;

// ---------------- async global->LDS 16B ----------------
__device__ __forceinline__ void glds16(const __bf16* g, __bf16* s) {
  __builtin_amdgcn_global_load_lds(
      (const __attribute__((address_space(1))) unsigned int*)(const void*)g,
      (__attribute__((address_space(3))) unsigned int*)(void*)s, 16, 0, 0);
}

// ---------------- fp32 -> bf16 convert ----------------
__global__ void cvt_kernel(const float* __restrict__ s, __bf16* __restrict__ d, int n4) {
  int i = blockIdx.x * 256 + threadIdx.x;
  if (i >= n4) return;
  float4 v = ((const float4*)s)[i];
  union { __bf16 b[4]; ushort4 u; } c;
  c.b[0] = (__bf16)v.x; c.b[1] = (__bf16)v.y; c.b[2] = (__bf16)v.z; c.b[3] = (__bf16)v.w;
  ((ushort4*)d)[i] = c.u;
}

// ---------------- RMSNorm (row of 2048, 256 threads) ----------------
__global__ __launch_bounds__(256)
void rmsnorm_kernel(const float* __restrict__ x, const float* __restrict__ w,
                    __bf16* __restrict__ out) {
  const int row = blockIdx.x, t = threadIdx.x;
  const float4* xr = (const float4*)(x + (size_t)row * DD);
  float4 a = xr[t], b = xr[t + 256];
  float s = a.x*a.x + a.y*a.y + a.z*a.z + a.w*a.w
          + b.x*b.x + b.y*b.y + b.z*b.z + b.w*b.w;
#pragma unroll
  for (int m = 1; m < 64; m <<= 1) s += __shfl_xor(s, m, 64);
  __shared__ float red[4];
  if ((t & 63) == 0) red[t >> 6] = s;
  __syncthreads();
  float tot = red[0] + red[1] + red[2] + red[3];
  float inv = 1.0f / (sqrtf(tot * (1.0f / 2048.0f) + 1e-6f) + 1e-6f);
  const float4* wr = (const float4*)w;
  float4 w0 = wr[t], w1 = wr[t + 256];
  __bf16* o = out + (size_t)row * DD;
  union { __bf16 bb[4]; ushort4 u; } c;
  c.bb[0] = (__bf16)(a.x*inv*w0.x); c.bb[1] = (__bf16)(a.y*inv*w0.y);
  c.bb[2] = (__bf16)(a.z*inv*w0.z); c.bb[3] = (__bf16)(a.w*inv*w0.w);
  ((ushort4*)o)[t] = c.u;
  c.bb[0] = (__bf16)(b.x*inv*w1.x); c.bb[1] = (__bf16)(b.y*inv*w1.y);
  c.bb[2] = (__bf16)(b.z*inv*w1.z); c.bb[3] = (__bf16)(b.w*inv*w1.w);
  ((ushort4*)o)[t + 256] = c.u;
}

// ---------------- NT GEMM: C[M,N] = A[M,K] * B[N,K]^T ----------------
// 128x128 tile, BK=64 (m97 structure), global_load_lds(16B) staging.
// Per K-step: 8 glds16 issues, 16 ds_read_b128, 32 MFMA between one barrier
// pair -> barrier-drain stall amortized 2x vs BK=32.
// Block swizzle: XCD (lid&7) owns m-band [xcd*4 .. xcd*4+3]; n walked in
// 4-strip chunks so each B-strip's 4 m-uses land in one 16-block window.
// EPI 0: Cb=(bf16)acc; EPI 1: Cf=Res+acc; EPI 2: Cb=(bf16)(silu(Cb)*acc)
template<int EPI>
__global__ __launch_bounds__(256)
void gemm_nt_kernel(const __bf16* __restrict__ A, const __bf16* __restrict__ Bm,
                    __bf16* Cb, const float* __restrict__ Res,
                    float* __restrict__ Cf, int M, int N, int K) {
  __shared__ __align__(16) __bf16 As[128 * 64];
  __shared__ __align__(16) __bf16 Bs[128 * 64];
  const int t = threadIdx.x;
  const int GM = M >> 7, GN = N >> 7;
  int m_t, n_t;
  if (GM == 32 && (GN & 3) == 0) {
    int lid = blockIdx.y * gridDim.x + blockIdx.x;
    int xcd = lid & 7, i = lid >> 3;
    int c = i >> 4, j = i & 15;
    m_t = xcd * 4 + (j & 3);
    n_t = c * 4 + (j >> 2);
  } else {
    m_t = blockIdx.y; n_t = blockIdx.x;
  }
  const int m0 = m_t * 128, n0 = n_t * 128;
  const int w = t >> 6, l = t & 63;
  const int wm = w & 1, wn = w >> 1;
  const int lm = l & 15, lq = l >> 4;
  // staging: tile slot = it*256 + t ; row = slot>>3 ; atom = slot&7 (8B atoms)
  // wave-uniform LDS base per issue = As + (it*256 + w*64) slots * 16B
  const int r0 = t >> 3;        // 0..31, +it*32 per issue
  const int a0 = t & 7;
  const __bf16* Ap = A + (size_t)(m0 + r0) * K + a0 * 8;
  const __bf16* Bp = Bm + (size_t)(n0 + r0) * K + a0 * 8;
  __bf16* AsW = As + w * 512;   // elements: w*1024B
  __bf16* BsW = Bs + w * 512;
  f32x4 acc[4][4] = {};
  for (int kt = 0; kt < K; kt += 64) {
    __syncthreads();
#pragma unroll
    for (int it = 0; it < 4; it++) {
      glds16(Ap + (size_t)(it * 32) * K + kt, AsW + it * 2048);
      glds16(Bp + (size_t)(it * 32) * K + kt, BsW + it * 2048);
    }
    __syncthreads();
    bf16x8 af[2][4], bfr[2][4];
#pragma unroll
    for (int kk = 0; kk < 2; kk++) {
#pragma unroll
      for (int i = 0; i < 4; i++)
        af[kk][i] = *(const bf16x8*)&As[(wm * 64 + i * 16 + lm) * 64 + kk * 32 + lq * 8];
#pragma unroll
      for (int j = 0; j < 4; j++)
        bfr[kk][j] = *(const bf16x8*)&Bs[(wn * 64 + j * 16 + lm) * 64 + kk * 32 + lq * 8];
    }
#pragma unroll
    for (int kk = 0; kk < 2; kk++)
#pragma unroll
      for (int i = 0; i < 4; i++)
#pragma unroll
        for (int j = 0; j < 4; j++)
          acc[i][j] = __builtin_amdgcn_mfma_f32_16x16x32_bf16(af[kk][i], bfr[kk][j], acc[i][j], 0, 0, 0);
  }
#pragma unroll
  for (int i = 0; i < 4; i++)
#pragma unroll
    for (int j = 0; j < 4; j++)
#pragma unroll
      for (int r = 0; r < 4; r++) {
        int row = m0 + wm * 64 + i * 16 + lq * 4 + r;
        int col = n0 + wn * 64 + j * 16 + lm;
        size_t idx = (size_t)row * N + col;
        if (EPI == 0) {
          Cb[idx] = (__bf16)acc[i][j][r];
        } else if (EPI == 1) {
          Cf[idx] = Res[idx] + acc[i][j][r];
        } else {
          float g = (float)Cb[idx];
          Cb[idx] = (__bf16)(g / (1.0f + __expf(-g)) * acc[i][j][r]);
        }
      }
}

// ---------------- rope: out = rot_half(x) * (pm0+pm1) ----------------
__global__ __launch_bounds__(256)
void rope_kernel(const __bf16* __restrict__ qkv, const float* __restrict__ pm,
                 __bf16* __restrict__ qo, __bf16* __restrict__ ko) {
  const int row = blockIdx.x, t = threadIdx.x;
  const int s = row & 2047;
  const __bf16* q = qkv + (size_t)row * QKVN;
  const float* p0 = pm + (size_t)s * DD;
  const float* p1 = p0 + (size_t)2048 * DD;
  __bf16* qr = qo + (size_t)row * DD;
#pragma unroll
  for (int jj = 0; jj < 8; jj++) {
    int i = t + jj * 256;
    float rot = (i < 1024) ? -(float)q[i + 1024] : (float)q[i - 1024];
    qr[i] = (__bf16)(rot * (p0[i] + p1[i]));
  }
  const __bf16* k = q + 2048;
  __bf16* kr = ko + (size_t)row * KVD;
  {
    int i = t;
    float rot = (i < 128) ? -(float)k[i + 128] : (float)k[i - 128];
    kr[i] = (__bf16)(rot * (p0[i] + p1[i]));
  }
}

// ---------------- attention v2: transposed-S flash ----------------
// S^T = K·Q^T (C-layout: lane=q-col, rows=k_t) -> exp in-register is directly
// the A-fragment (k-permuted) of the PV 16x16x32 MFMA. No P through LDS.
// softmax = e/(sum e + 1): no max-rescale needed. grid (S/128, H, B).
__global__ __launch_bounds__(256)
void attn_kernel(const __bf16* __restrict__ Q, const __bf16* __restrict__ Kb,
                 const __bf16* __restrict__ QKV, __bf16* __restrict__ O) {
  __shared__ __align__(16) __bf16 sQ[128 * 72];
  __shared__ __align__(16) __bf16 sK[64 * 72];
  __shared__ __align__(16) __bf16 sV[64 * 72];   // [d][k] (V^T)
  __shared__ float sDen[128];
  const int t = threadIdx.x, l = t & 63, w = t >> 6;
  const int lm = l & 15, lq = l >> 4;
  const int q0 = blockIdx.x * 128;
  const int h = blockIdx.y, b = blockIdx.z;
  const int p = h & 3;                 // kv slice: head h uses dims p*64..p*64+64
  const float scale = 1.0f / (16.0f + 1e-6f);
  {
    const int qr = t >> 3, qc = (t & 7) * 8;
#pragma unroll
    for (int it = 0; it < 4; it++) {
      size_t base = ((size_t)(b * 2048 + q0 + qr + it * 32)) * DD + h * 64 + qc;
      *(uint4*)&sQ[(qr + it * 32) * 72 + qc] = *(const uint4*)(Q + base);
    }
  }
  f32x4 oacc[2][4] = {};                 // [q_j][d_n]
  float dsum[2] = {0.f, 0.f};            // per-lane partial denom, q = q_j*16+lm
  const int ksr = t >> 2, ksc = (t & 3) * 16;
  for (int kt = 0; kt < 2048; kt += 64) {
    const __bf16* krow = Kb + ((size_t)(b * 2048 + kt + ksr)) * KVD + p * 64 + ksc;
    uint4 kv0 = *(const uint4*)(krow);
    uint4 kv1 = *(const uint4*)(krow + 8);
    // V column-mode: lane = d (coalesced), wave w covers k = w*16..+15
    unsigned int vpack[8];
    {
      const __bf16* vbase = QKV + ((size_t)(b * 2048 + kt + w * 16)) * QKVN + 2304 + p * 64 + l;
#pragma unroll
      for (int j2 = 0; j2 < 8; j2++) {
        unsigned int u0 = *(const unsigned short*)(vbase + (size_t)(2 * j2) * QKVN);
        unsigned int u1 = *(const unsigned short*)(vbase + (size_t)(2 * j2 + 1) * QKVN);
        vpack[j2] = u0 | (u1 << 16);
      }
    }
    __syncthreads();
    *(uint4*)&sK[ksr * 72 + ksc] = kv0;
    *(uint4*)&sK[ksr * 72 + ksc + 8] = kv1;
    *(uint4*)&sV[l * 72 + w * 16] = *(uint4*)&vpack[0];
    *(uint4*)&sV[l * 72 + w * 16 + 8] = *(uint4*)&vpack[4];
    __syncthreads();
    // Q fragments (B-operand of S^T mfma), shared across kt chunks
    bf16x8 bQ[2][2];
#pragma unroll
    for (int q_j = 0; q_j < 2; q_j++)
#pragma unroll
      for (int kk = 0; kk < 2; kk++)
        bQ[q_j][kk] = *(const bf16x8*)&sQ[(w * 32 + q_j * 16 + lm) * 72 + kk * 32 + lq * 8];
#pragma unroll
    for (int kt2 = 0; kt2 < 2; kt2++) {  // pairs of 16-row k_t chunks
      union { bf16x8 v; __bf16 e[8]; } pA[2];
#pragma unroll
      for (int c = 0; c < 2; c++) {
        const int kt_i = kt2 * 2 + c;
        f32x4 sacc[2] = {};
#pragma unroll
        for (int kk = 0; kk < 2; kk++) {
          bf16x8 aK = *(const bf16x8*)&sK[(kt_i * 16 + lm) * 72 + kk * 32 + lq * 8];
#pragma unroll
          for (int q_j = 0; q_j < 2; q_j++)
            sacc[q_j] = __builtin_amdgcn_mfma_f32_16x16x32_bf16(aK, bQ[q_j][kk], sacc[q_j], 0, 0, 0);
        }
#pragma unroll
        for (int q_j = 0; q_j < 2; q_j++)
#pragma unroll
          for (int r = 0; r < 4; r++) {
            float e = __expf(sacc[q_j][r] * scale);
            dsum[q_j] += e;
            pA[q_j].e[c * 4 + r] = (__bf16)e;
          }
      }
      // PV: B-frag k-permuted to match pA: j 0..3 <- k=kt2*32+lq*4+j, j 4..7 <- +16
#pragma unroll
      for (int d_n = 0; d_n < 4; d_n++) {
        union { bf16x8 v; bf16x4 h[2]; } bV;
        const __bf16* vb = &sV[(d_n * 16 + lm) * 72 + kt2 * 32 + lq * 4];
        bV.h[0] = *(const bf16x4*)(vb);
        bV.h[1] = *(const bf16x4*)(vb + 16);
#pragma unroll
        for (int q_j = 0; q_j < 2; q_j++)
          oacc[q_j][d_n] = __builtin_amdgcn_mfma_f32_16x16x32_bf16(pA[q_j].v, bV.v, oacc[q_j][d_n], 0, 0, 0);
      }
    }
  }
  // denom: reduce over lq groups (lanes lm, lm+16, lm+32, lm+48 share q)
#pragma unroll
  for (int q_j = 0; q_j < 2; q_j++) {
    dsum[q_j] += __shfl_xor(dsum[q_j], 16, 64);
    dsum[q_j] += __shfl_xor(dsum[q_j], 32, 64);
  }
  if (l < 16) {
    sDen[w * 32 + l] = dsum[0];
    sDen[w * 32 + 16 + l] = dsum[1];
  }
  __syncthreads();
#pragma unroll
  for (int q_j = 0; q_j < 2; q_j++)
#pragma unroll
    for (int d_n = 0; d_n < 4; d_n++)
#pragma unroll
      for (int r = 0; r < 4; r++) {
        int rloc = w * 32 + q_j * 16 + lq * 4 + r;
        int row = q0 + rloc;
        int col = h * 64 + d_n * 16 + lm;
        O[((size_t)(b * 2048 + row)) * DD + col] = (__bf16)(oacc[q_j][d_n][r] / (sDen[rloc] + 1.0f));
      }
}

// ---------------------------------------------------------------------------
extern "C" void kernel_launch(void* const* d_in, const int* in_sizes, int n_in,
                              void* d_out, int out_size, void* d_ws, size_t ws_size,
                              hipStream_t stream) {
  if (ws_size < WS_NEED) return;

  const float* x    = (const float*)d_in[0];
  const float* pm   = (const float*)d_in[1];
  const float* w_na = (const float*)d_in[2];
  const float* w_nf = (const float*)d_in[3];
  const float* wq   = (const float*)d_in[4];
  const float* wk   = (const float*)d_in[5];
  const float* wv   = (const float*)d_in[6];
  const float* wo   = (const float*)d_in[7];
  const float* wg   = (const float*)d_in[8];
  const float* wu   = (const float*)d_in[9];
  const float* wd   = (const float*)d_in[10];

  char* ws = (char*)d_ws;
  __bf16* wqkv_b = (__bf16*)(ws + OFF_WQKV);
  __bf16* wo_b   = (__bf16*)(ws + OFF_WO);
  __bf16* wg_b   = (__bf16*)(ws + OFF_WG);
  __bf16* wu_b   = (__bf16*)(ws + OFF_WU);
  __bf16* wdn_b  = (__bf16*)(ws + OFF_WDN);
  __bf16* h_b    = (__bf16*)(ws + OFF_H);
  __bf16* qkv_b  = (__bf16*)(ws + OFF_QKV);
  __bf16* q_b    = (__bf16*)(ws + OFF_Q);
  __bf16* k_b    = (__bf16*)(ws + OFF_K);
  __bf16* act_b  = (__bf16*)(ws + OFF_ACT);
  float*  x1     = (float*)d_out;

  cvt_kernel<<<4096, 256, 0, stream>>>(wq, wqkv_b, 1048576);
  cvt_kernel<<<512, 256, 0, stream>>>(wk, wqkv_b + (size_t)2048 * 2048, 131072);
  cvt_kernel<<<512, 256, 0, stream>>>(wv, wqkv_b + (size_t)2304 * 2048, 131072);
  cvt_kernel<<<4096, 256, 0, stream>>>(wo, wo_b, 1048576);
  cvt_kernel<<<11264, 256, 0, stream>>>(wg, wg_b, 2883584);
  cvt_kernel<<<11264, 256, 0, stream>>>(wu, wu_b, 2883584);
  cvt_kernel<<<11264, 256, 0, stream>>>(wd, wdn_b, 2883584);

  // ---- attention sublayer ----
  rmsnorm_kernel<<<4096, 256, 0, stream>>>(x, w_na, h_b);
  gemm_nt_kernel<0><<<dim3(20, 32), 256, 0, stream>>>(h_b, wqkv_b, qkv_b, nullptr, nullptr,
                                                      RR, QKVN, DD);
  rope_kernel<<<4096, 256, 0, stream>>>(qkv_b, pm, q_b, k_b);
  attn_kernel<<<dim3(16, 32, 2), 256, 0, stream>>>(q_b, k_b, qkv_b, h_b);
  gemm_nt_kernel<1><<<dim3(16, 32), 256, 0, stream>>>(h_b, wo_b, nullptr, x, x1,
                                                      RR, DD, DD);
  // ---- feedforward sublayer ----
  rmsnorm_kernel<<<4096, 256, 0, stream>>>(x1, w_nf, q_b);
  gemm_nt_kernel<0><<<dim3(44, 32), 256, 0, stream>>>(q_b, wg_b, act_b, nullptr, nullptr,
                                                      RR, DFF, DD);
  gemm_nt_kernel<2><<<dim3(44, 32), 256, 0, stream>>>(q_b, wu_b, act_b, nullptr, nullptr,
                                                      RR, DFF, DD);
  gemm_nt_kernel<1><<<dim3(16, 32), 256, 0, stream>>>(act_b, wdn_b, nullptr, x1, x1,
                                                      RR, DD, DFF);
}

// Round 2
// 1010.053 us; speedup vs baseline: 1.0484x; 1.0484x over previous
//
#include <hip/hip_runtime.h>

// ---------------------------------------------------------------------------
// TransformerBlock: B=2,S=2048,D=2048,H=32,HD=64,G=8,KV=256,DFF=5632
// fp32 in/out. R2: GEMMs moved to 256x256 8-wave counted-vmcnt phase pipeline
// (T3+T4) + LDS XOR swizzle (T2, pre-swizzled global src per rule #21) +
// setprio around MFMA clusters (T5) + bijective XCD block swizzle (T1).
// Attention / rmsnorm / rope unchanged from the 988us baseline.
// ---------------------------------------------------------------------------

typedef __attribute__((ext_vector_type(8))) __bf16 bf16x8;
typedef __attribute__((ext_vector_type(4))) __bf16 bf16x4;
typedef __attribute__((ext_vector_type(4))) float f32x4;

#define RR 4096      // B*S rows
#define DD 2048
#define KVD 256
#define QKVN 2560    // 2048 q + 256 k + 256 v
#define DFF 5632

// ---------------- workspace layout (bytes) ----------------
static const size_t OFF_WQKV = 0;              // bf16 [2560,2048]
static const size_t OFF_WO   = 10485760;       // bf16 [2048,2048]
static const size_t OFF_WG   = 18874368;       // bf16 [5632,2048]
static const size_t OFF_WU   = 41943040;       // bf16 [5632,2048]
static const size_t OFF_WDN  = 65011712;       // bf16 [2048,5632]
static const size_t OFF_H    = 88080384;       // bf16 [4096,2048]  (h, then attn_out)
static const size_t OFF_QKV  = 104857600;      // bf16 [4096,2560]
static const size_t OFF_Q    = 125829120;      // bf16 [4096,2048]  (q_rope, then h2)
static const size_t OFF_K    = 142606336;      // bf16 [4096,256]
static const size_t OFF_ACT  = 144703488;      // bf16 [4096,5632]  (gate tmp, then silu*up)
static const size_t WS_NEED  = 190840832;

// ---------------- async global->LDS 16B ----------------
__device__ __forceinline__ void glds16(const __bf16* g, __bf16* s) {
  __builtin_amdgcn_global_load_lds(
      (const __attribute__((address_space(1))) unsigned int*)(const void*)g,
      (__attribute__((address_space(3))) unsigned int*)(void*)s, 16, 0, 0);
}

// ---------------- fp32 -> bf16 convert ----------------
__global__ void cvt_kernel(const float* __restrict__ s, __bf16* __restrict__ d, int n4) {
  int i = blockIdx.x * 256 + threadIdx.x;
  if (i >= n4) return;
  float4 v = ((const float4*)s)[i];
  union { __bf16 b[4]; ushort4 u; } c;
  c.b[0] = (__bf16)v.x; c.b[1] = (__bf16)v.y; c.b[2] = (__bf16)v.z; c.b[3] = (__bf16)v.w;
  ((ushort4*)d)[i] = c.u;
}

// ---------------- RMSNorm (row of 2048, 256 threads) ----------------
__global__ __launch_bounds__(256)
void rmsnorm_kernel(const float* __restrict__ x, const float* __restrict__ w,
                    __bf16* __restrict__ out) {
  const int row = blockIdx.x, t = threadIdx.x;
  const float4* xr = (const float4*)(x + (size_t)row * DD);
  float4 a = xr[t], b = xr[t + 256];
  float s = a.x*a.x + a.y*a.y + a.z*a.z + a.w*a.w
          + b.x*b.x + b.y*b.y + b.z*b.z + b.w*b.w;
#pragma unroll
  for (int m = 1; m < 64; m <<= 1) s += __shfl_xor(s, m, 64);
  __shared__ float red[4];
  if ((t & 63) == 0) red[t >> 6] = s;
  __syncthreads();
  float tot = red[0] + red[1] + red[2] + red[3];
  float inv = 1.0f / (sqrtf(tot * (1.0f / 2048.0f) + 1e-6f) + 1e-6f);
  const float4* wr = (const float4*)w;
  float4 w0 = wr[t], w1 = wr[t + 256];
  __bf16* o = out + (size_t)row * DD;
  union { __bf16 bb[4]; ushort4 u; } c;
  c.bb[0] = (__bf16)(a.x*inv*w0.x); c.bb[1] = (__bf16)(a.y*inv*w0.y);
  c.bb[2] = (__bf16)(a.z*inv*w0.z); c.bb[3] = (__bf16)(a.w*inv*w0.w);
  ((ushort4*)o)[t] = c.u;
  c.bb[0] = (__bf16)(b.x*inv*w1.x); c.bb[1] = (__bf16)(b.y*inv*w1.y);
  c.bb[2] = (__bf16)(b.z*inv*w1.z); c.bb[3] = (__bf16)(b.w*inv*w1.w);
  ((ushort4*)o)[t + 256] = c.u;
}

// ---------------- NT GEMM 256x256: C[M,N] = A[M,K] * B[N,K]^T ----------------
// 8 waves (2Mx4N), per-wave 128x64 out. BK=64, 2 LDS tile-buffers (128 KiB).
// 4 phases/K-tile: (h0,kk0)(h1,kk0)(h0,kk1)(h1,kk1); raw s_barrier pairs,
// setprio(1) around 16-MFMA clusters. Staging: per tile kt issues
// ph1:Ah1(kt+1) ph2:Bh0(kt+1) ph3:Bh1(kt+1) ph4:Ah0(kt+2) -> boundary
// s_waitcnt vmcnt(2) (never 0 mid-loop). LDS rows 128B, 8x16B slots; read slot
// (kk*4+lq)^(row&7); global source pre-swizzled with the same involution so
// global_load_lds' linear dest yields the swizzled layout (rule #21).
// EPI 0: Cb=(bf16)acc; EPI 1: Cf=Res+acc; EPI 2: Cb=(bf16)(silu(Cb)*acc)
template<int EPI>
__global__ __launch_bounds__(512, 2)
void gemm256_kernel(const __bf16* __restrict__ A, const __bf16* __restrict__ Bm,
                    __bf16* Cb, const float* __restrict__ Res,
                    float* __restrict__ Cf, int M, int N, int K) {
  __shared__ __align__(16) __bf16 LA[2][256 * 64];
  __shared__ __align__(16) __bf16 LB[2][256 * 64];
  const int t = threadIdx.x, w = t >> 6, l = t & 63;
  const int lm = l & 15, lq = l >> 4;
  const int wm = w & 1, wn = w >> 1;           // 2 x 4 wave grid
  const int NT = K >> 6;
  // bijective XCD swizzle (m204)
  const int nwg = gridDim.x * gridDim.y;
  const int lid = blockIdx.y * gridDim.x + blockIdx.x;
  const int q8 = nwg >> 3, r8 = nwg & 7;
  const int xcd = lid & 7, j0 = lid >> 3;
  const int wg = (xcd < r8 ? xcd * (q8 + 1) : r8 * (q8 + 1) + (xcd - r8) * q8) + j0;
  const int GN = N >> 8;
  const int m0 = (wg / GN) << 8, n0 = (wg % GN) << 8;

  // staging: chunk = 64 rows x 128B; thread -> row w*8+(l>>3), phys slot l&7,
  // global slot (l&7)^(l>>3)  (tile-row&7 == l>>3)
  const int srow = l >> 3, sslot = (l & 7) ^ srow;
  const __bf16* Ag = A + (size_t)(m0 + w * 8 + srow) * K + sslot * 8;
  const __bf16* Bg = Bm + (size_t)(n0 + w * 8 + srow) * K + sslot * 8;
  const int dstoff = w * 8 * 64;               // elements within chunk base

  // fragment read bases (element offsets); swizzled slot per kk
  const int aRow = (wm * 128 + lm) * 64;
  const int bRow = (wn * 64 + lm) * 64;
  const int sl0 = ((lq) ^ (lm & 7)) << 3;          // kk=0
  const int sl1 = ((4 + lq) ^ (lm & 7)) << 3;      // kk=1

  f32x4 acc[8][4] = {};
  bf16x8 aa[4], bb[4];

#define ST_A(bufi, kti, c) glds16(Ag + (size_t)((c) * 64) * K + (size_t)(kti) * 64, \
                                  &LA[bufi][(c) * 4096 + dstoff])
#define ST_B(bufi, kti, c) glds16(Bg + (size_t)((c) * 64) * K + (size_t)(kti) * 64, \
                                  &LB[bufi][(c) * 4096 + dstoff])
#define RD_A(i, kkslot) *(const bf16x8*)&LA[buf][aRow + (i) * 1024 + (kkslot)]
#define RD_B(j, kkslot) *(const bf16x8*)&LB[buf][bRow + (j) * 1024 + (kkslot)]
#define CLUSTER16(I0)                                                              \
  __builtin_amdgcn_s_setprio(1);                                                   \
  _Pragma("unroll") for (int jj = 0; jj < 4; ++jj) {                               \
    acc[(I0) + 0][jj] = __builtin_amdgcn_mfma_f32_16x16x32_bf16(aa[0], bb[jj], acc[(I0) + 0][jj], 0, 0, 0); \
    acc[(I0) + 1][jj] = __builtin_amdgcn_mfma_f32_16x16x32_bf16(aa[1], bb[jj], acc[(I0) + 1][jj], 0, 0, 0); \
    acc[(I0) + 2][jj] = __builtin_amdgcn_mfma_f32_16x16x32_bf16(aa[2], bb[jj], acc[(I0) + 2][jj], 0, 0, 0); \
    acc[(I0) + 3][jj] = __builtin_amdgcn_mfma_f32_16x16x32_bf16(aa[3], bb[jj], acc[(I0) + 3][jj], 0, 0, 0); \
  }                                                                                \
  __builtin_amdgcn_s_setprio(0);
#define BAR() do { __builtin_amdgcn_s_barrier(); asm volatile("" ::: "memory"); } while (0)

  // ---- prologue: tile 0 full + Ah0(tile 1); NT >= 2 always here ----
  ST_A(0, 0, 0); ST_A(0, 0, 1); ST_A(0, 0, 2); ST_A(0, 0, 3);
  ST_B(0, 0, 0); ST_B(0, 0, 1); ST_B(0, 0, 2); ST_B(0, 0, 3);
  ST_A(1, 1, 0); ST_A(1, 1, 1);
  asm volatile("s_waitcnt vmcnt(2)" ::: "memory");
  __builtin_amdgcn_s_barrier();

  for (int kt = 0; kt < NT; ++kt) {
    const int buf = kt & 1, nb = buf ^ 1;
    // ---- ph1: (h0, kk0) ----
    aa[0] = RD_A(0, sl0); aa[1] = RD_A(1, sl0); aa[2] = RD_A(2, sl0); aa[3] = RD_A(3, sl0);
    bb[0] = RD_B(0, sl0); bb[1] = RD_B(1, sl0); bb[2] = RD_B(2, sl0); bb[3] = RD_B(3, sl0);
    if (kt + 1 < NT) { ST_A(nb, kt + 1, 2); ST_A(nb, kt + 1, 3); }   // Ah1(kt+1)
    BAR();
    CLUSTER16(0);
    BAR();
    // ---- ph2: (h1, kk0) ----
    aa[0] = RD_A(4, sl0); aa[1] = RD_A(5, sl0); aa[2] = RD_A(6, sl0); aa[3] = RD_A(7, sl0);
    if (kt + 1 < NT) { ST_B(nb, kt + 1, 0); ST_B(nb, kt + 1, 1); }   // Bh0(kt+1)
    BAR();
    CLUSTER16(4);
    BAR();
    // ---- ph3: (h0, kk1) ----
    aa[0] = RD_A(0, sl1); aa[1] = RD_A(1, sl1); aa[2] = RD_A(2, sl1); aa[3] = RD_A(3, sl1);
    bb[0] = RD_B(0, sl1); bb[1] = RD_B(1, sl1); bb[2] = RD_B(2, sl1); bb[3] = RD_B(3, sl1);
    if (kt + 1 < NT) { ST_B(nb, kt + 1, 2); ST_B(nb, kt + 1, 3); }   // Bh1(kt+1)
    BAR();
    CLUSTER16(0);
    BAR();
    // ---- ph4: (h1, kk1) ----
    aa[0] = RD_A(4, sl1); aa[1] = RD_A(5, sl1); aa[2] = RD_A(6, sl1); aa[3] = RD_A(7, sl1);
    if (kt + 2 < NT) { ST_A(buf, kt + 2, 0); ST_A(buf, kt + 2, 1); } // Ah0(kt+2): h0 of buf done at ph3
    BAR();
    CLUSTER16(4);
    // ---- tile boundary: counted wait (tile kt+1 landed; Ah0(kt+2) may float) ----
    if (kt + 1 < NT) {
      if (kt + 2 < NT) asm volatile("s_waitcnt vmcnt(2)" ::: "memory");
      else             asm volatile("s_waitcnt vmcnt(0)" ::: "memory");
    }
    BAR();
  }

  // ---- epilogue ----
#pragma unroll
  for (int i = 0; i < 8; i++)
#pragma unroll
    for (int j = 0; j < 4; j++)
#pragma unroll
      for (int r = 0; r < 4; r++) {
        int row = m0 + wm * 128 + i * 16 + lq * 4 + r;
        int col = n0 + wn * 64 + j * 16 + lm;
        size_t idx = (size_t)row * N + col;
        if (EPI == 0) {
          Cb[idx] = (__bf16)acc[i][j][r];
        } else if (EPI == 1) {
          Cf[idx] = Res[idx] + acc[i][j][r];
        } else {
          float g = (float)Cb[idx];
          Cb[idx] = (__bf16)(g / (1.0f + __expf(-g)) * acc[i][j][r]);
        }
      }
#undef ST_A
#undef ST_B
#undef RD_A
#undef RD_B
#undef CLUSTER16
#undef BAR
}

// ---------------- rope: out = rot_half(x) * (pm0+pm1) ----------------
__global__ __launch_bounds__(256)
void rope_kernel(const __bf16* __restrict__ qkv, const float* __restrict__ pm,
                 __bf16* __restrict__ qo, __bf16* __restrict__ ko) {
  const int row = blockIdx.x, t = threadIdx.x;
  const int s = row & 2047;
  const __bf16* q = qkv + (size_t)row * QKVN;
  const float* p0 = pm + (size_t)s * DD;
  const float* p1 = p0 + (size_t)2048 * DD;
  __bf16* qr = qo + (size_t)row * DD;
#pragma unroll
  for (int jj = 0; jj < 8; jj++) {
    int i = t + jj * 256;
    float rot = (i < 1024) ? -(float)q[i + 1024] : (float)q[i - 1024];
    qr[i] = (__bf16)(rot * (p0[i] + p1[i]));
  }
  const __bf16* k = q + 2048;
  __bf16* kr = ko + (size_t)row * KVD;
  {
    int i = t;
    float rot = (i < 128) ? -(float)k[i + 128] : (float)k[i - 128];
    kr[i] = (__bf16)(rot * (p0[i] + p1[i]));
  }
}

// ---------------- attention v2: transposed-S flash ----------------
// S^T = K·Q^T (C-layout: lane=q-col, rows=k_t) -> exp in-register is directly
// the A-fragment (k-permuted) of the PV 16x16x32 MFMA. No P through LDS.
// softmax = e/(sum e + 1): no max-rescale needed. grid (S/128, H, B).
__global__ __launch_bounds__(256)
void attn_kernel(const __bf16* __restrict__ Q, const __bf16* __restrict__ Kb,
                 const __bf16* __restrict__ QKV, __bf16* __restrict__ O) {
  __shared__ __align__(16) __bf16 sQ[128 * 72];
  __shared__ __align__(16) __bf16 sK[64 * 72];
  __shared__ __align__(16) __bf16 sV[64 * 72];   // [d][k] (V^T)
  __shared__ float sDen[128];
  const int t = threadIdx.x, l = t & 63, w = t >> 6;
  const int lm = l & 15, lq = l >> 4;
  const int q0 = blockIdx.x * 128;
  const int h = blockIdx.y, b = blockIdx.z;
  const int p = h & 3;                 // kv slice: head h uses dims p*64..p*64+64
  const float scale = 1.0f / (16.0f + 1e-6f);
  {
    const int qr = t >> 3, qc = (t & 7) * 8;
#pragma unroll
    for (int it = 0; it < 4; it++) {
      size_t base = ((size_t)(b * 2048 + q0 + qr + it * 32)) * DD + h * 64 + qc;
      *(uint4*)&sQ[(qr + it * 32) * 72 + qc] = *(const uint4*)(Q + base);
    }
  }
  f32x4 oacc[2][4] = {};                 // [q_j][d_n]
  float dsum[2] = {0.f, 0.f};            // per-lane partial denom, q = q_j*16+lm
  const int ksr = t >> 2, ksc = (t & 3) * 16;
  for (int kt = 0; kt < 2048; kt += 64) {
    const __bf16* krow = Kb + ((size_t)(b * 2048 + kt + ksr)) * KVD + p * 64 + ksc;
    uint4 kv0 = *(const uint4*)(krow);
    uint4 kv1 = *(const uint4*)(krow + 8);
    // V column-mode: lane = d (coalesced), wave w covers k = w*16..+15
    unsigned int vpack[8];
    {
      const __bf16* vbase = QKV + ((size_t)(b * 2048 + kt + w * 16)) * QKVN + 2304 + p * 64 + l;
#pragma unroll
      for (int j2 = 0; j2 < 8; j2++) {
        unsigned int u0 = *(const unsigned short*)(vbase + (size_t)(2 * j2) * QKVN);
        unsigned int u1 = *(const unsigned short*)(vbase + (size_t)(2 * j2 + 1) * QKVN);
        vpack[j2] = u0 | (u1 << 16);
      }
    }
    __syncthreads();
    *(uint4*)&sK[ksr * 72 + ksc] = kv0;
    *(uint4*)&sK[ksr * 72 + ksc + 8] = kv1;
    *(uint4*)&sV[l * 72 + w * 16] = *(uint4*)&vpack[0];
    *(uint4*)&sV[l * 72 + w * 16 + 8] = *(uint4*)&vpack[4];
    __syncthreads();
    // Q fragments (B-operand of S^T mfma), shared across kt chunks
    bf16x8 bQ[2][2];
#pragma unroll
    for (int q_j = 0; q_j < 2; q_j++)
#pragma unroll
      for (int kk = 0; kk < 2; kk++)
        bQ[q_j][kk] = *(const bf16x8*)&sQ[(w * 32 + q_j * 16 + lm) * 72 + kk * 32 + lq * 8];
#pragma unroll
    for (int kt2 = 0; kt2 < 2; kt2++) {  // pairs of 16-row k_t chunks
      union { bf16x8 v; __bf16 e[8]; } pA[2];
#pragma unroll
      for (int c = 0; c < 2; c++) {
        const int kt_i = kt2 * 2 + c;
        f32x4 sacc[2] = {};
#pragma unroll
        for (int kk = 0; kk < 2; kk++) {
          bf16x8 aK = *(const bf16x8*)&sK[(kt_i * 16 + lm) * 72 + kk * 32 + lq * 8];
#pragma unroll
          for (int q_j = 0; q_j < 2; q_j++)
            sacc[q_j] = __builtin_amdgcn_mfma_f32_16x16x32_bf16(aK, bQ[q_j][kk], sacc[q_j], 0, 0, 0);
        }
#pragma unroll
        for (int q_j = 0; q_j < 2; q_j++)
#pragma unroll
          for (int r = 0; r < 4; r++) {
            float e = __expf(sacc[q_j][r] * scale);
            dsum[q_j] += e;
            pA[q_j].e[c * 4 + r] = (__bf16)e;
          }
      }
      // PV: B-frag k-permuted to match pA: j 0..3 <- k=kt2*32+lq*4+j, j 4..7 <- +16
#pragma unroll
      for (int d_n = 0; d_n < 4; d_n++) {
        union { bf16x8 v; bf16x4 h[2]; } bV;
        const __bf16* vb = &sV[(d_n * 16 + lm) * 72 + kt2 * 32 + lq * 4];
        bV.h[0] = *(const bf16x4*)(vb);
        bV.h[1] = *(const bf16x4*)(vb + 16);
#pragma unroll
        for (int q_j = 0; q_j < 2; q_j++)
          oacc[q_j][d_n] = __builtin_amdgcn_mfma_f32_16x16x32_bf16(pA[q_j].v, bV.v, oacc[q_j][d_n], 0, 0, 0);
      }
    }
  }
  // denom: reduce over lq groups (lanes lm, lm+16, lm+32, lm+48 share q)
#pragma unroll
  for (int q_j = 0; q_j < 2; q_j++) {
    dsum[q_j] += __shfl_xor(dsum[q_j], 16, 64);
    dsum[q_j] += __shfl_xor(dsum[q_j], 32, 64);
  }
  if (l < 16) {
    sDen[w * 32 + l] = dsum[0];
    sDen[w * 32 + 16 + l] = dsum[1];
  }
  __syncthreads();
#pragma unroll
  for (int q_j = 0; q_j < 2; q_j++)
#pragma unroll
    for (int d_n = 0; d_n < 4; d_n++)
#pragma unroll
      for (int r = 0; r < 4; r++) {
        int rloc = w * 32 + q_j * 16 + lq * 4 + r;
        int row = q0 + rloc;
        int col = h * 64 + d_n * 16 + lm;
        O[((size_t)(b * 2048 + row)) * DD + col] = (__bf16)(oacc[q_j][d_n][r] / (sDen[rloc] + 1.0f));
      }
}

// ---------------------------------------------------------------------------
extern "C" void kernel_launch(void* const* d_in, const int* in_sizes, int n_in,
                              void* d_out, int out_size, void* d_ws, size_t ws_size,
                              hipStream_t stream) {
  if (ws_size < WS_NEED) return;

  const float* x    = (const float*)d_in[0];
  const float* pm   = (const float*)d_in[1];
  const float* w_na = (const float*)d_in[2];
  const float* w_nf = (const float*)d_in[3];
  const float* wq   = (const float*)d_in[4];
  const float* wk   = (const float*)d_in[5];
  const float* wv   = (const float*)d_in[6];
  const float* wo   = (const float*)d_in[7];
  const float* wg   = (const float*)d_in[8];
  const float* wu   = (const float*)d_in[9];
  const float* wd   = (const float*)d_in[10];

  char* ws = (char*)d_ws;
  __bf16* wqkv_b = (__bf16*)(ws + OFF_WQKV);
  __bf16* wo_b   = (__bf16*)(ws + OFF_WO);
  __bf16* wg_b   = (__bf16*)(ws + OFF_WG);
  __bf16* wu_b   = (__bf16*)(ws + OFF_WU);
  __bf16* wdn_b  = (__bf16*)(ws + OFF_WDN);
  __bf16* h_b    = (__bf16*)(ws + OFF_H);
  __bf16* qkv_b  = (__bf16*)(ws + OFF_QKV);
  __bf16* q_b    = (__bf16*)(ws + OFF_Q);
  __bf16* k_b    = (__bf16*)(ws + OFF_K);
  __bf16* act_b  = (__bf16*)(ws + OFF_ACT);
  float*  x1     = (float*)d_out;

  cvt_kernel<<<4096, 256, 0, stream>>>(wq, wqkv_b, 1048576);
  cvt_kernel<<<512, 256, 0, stream>>>(wk, wqkv_b + (size_t)2048 * 2048, 131072);
  cvt_kernel<<<512, 256, 0, stream>>>(wv, wqkv_b + (size_t)2304 * 2048, 131072);
  cvt_kernel<<<4096, 256, 0, stream>>>(wo, wo_b, 1048576);
  cvt_kernel<<<11264, 256, 0, stream>>>(wg, wg_b, 2883584);
  cvt_kernel<<<11264, 256, 0, stream>>>(wu, wu_b, 2883584);
  cvt_kernel<<<11264, 256, 0, stream>>>(wd, wdn_b, 2883584);

  // ---- attention sublayer ----
  rmsnorm_kernel<<<4096, 256, 0, stream>>>(x, w_na, h_b);
  gemm256_kernel<0><<<dim3(10, 16), 512, 0, stream>>>(h_b, wqkv_b, qkv_b, nullptr, nullptr,
                                                      RR, QKVN, DD);
  rope_kernel<<<4096, 256, 0, stream>>>(qkv_b, pm, q_b, k_b);
  attn_kernel<<<dim3(16, 32, 2), 256, 0, stream>>>(q_b, k_b, qkv_b, h_b);
  gemm256_kernel<1><<<dim3(8, 16), 512, 0, stream>>>(h_b, wo_b, nullptr, x, x1,
                                                     RR, DD, DD);
  // ---- feedforward sublayer ----
  rmsnorm_kernel<<<4096, 256, 0, stream>>>(x1, w_nf, q_b);
  gemm256_kernel<0><<<dim3(22, 16), 512, 0, stream>>>(q_b, wg_b, act_b, nullptr, nullptr,
                                                      RR, DFF, DD);
  gemm256_kernel<2><<<dim3(22, 16), 512, 0, stream>>>(q_b, wu_b, act_b, nullptr, nullptr,
                                                      RR, DFF, DD);
  gemm256_kernel<1><<<dim3(8, 16), 512, 0, stream>>>(act_b, wdn_b, nullptr, x1, x1,
                                                     RR, DD, DFF);
}

// Round 3
// 994.858 us; speedup vs baseline: 1.0644x; 1.0153x over previous
//
#include <hip/hip_runtime.h>

// ---------------------------------------------------------------------------
// TransformerBlock: B=2,S=2048,D=2048,H=32,HD=64,G=8,KV=256,DFF=5632
// fp32 in/out. R3: gemm256 inner loop rebuilt on the m201 recipe:
//  - inline-asm ds_read_b128 (compiler can't see LDS-DMA alias -> no forced
//    vmcnt(0) drains), lgkmcnt(0)+sched_barrier(0) before MFMA clusters
//  - prefetch distance 2 tiles: tile kt+1 fully resident at kt start; kt+2
//    staged into dead regions (6 chunks at ph4, A1/A3 at next ph1);
//    one s_waitcnt vmcnt(6) per K-tile, never 0 mid-loop.
// Attention / rmsnorm / rope unchanged.
// ---------------------------------------------------------------------------

typedef __attribute__((ext_vector_type(8))) __bf16 bf16x8;
typedef __attribute__((ext_vector_type(4))) __bf16 bf16x4;
typedef __attribute__((ext_vector_type(4))) float f32x4;

#define RR 4096      // B*S rows
#define DD 2048
#define KVD 256
#define QKVN 2560    // 2048 q + 256 k + 256 v
#define DFF 5632

// ---------------- workspace layout (bytes) ----------------
static const size_t OFF_WQKV = 0;              // bf16 [2560,2048]
static const size_t OFF_WO   = 10485760;       // bf16 [2048,2048]
static const size_t OFF_WG   = 18874368;       // bf16 [5632,2048]
static const size_t OFF_WU   = 41943040;       // bf16 [5632,2048]
static const size_t OFF_WDN  = 65011712;       // bf16 [2048,5632]
static const size_t OFF_H    = 88080384;       // bf16 [4096,2048]  (h, then attn_out)
static const size_t OFF_QKV  = 104857600;      // bf16 [4096,2560]
static const size_t OFF_Q    = 125829120;      // bf16 [4096,2048]  (q_rope, then h2)
static const size_t OFF_K    = 142606336;      // bf16 [4096,256]
static const size_t OFF_ACT  = 144703488;      // bf16 [4096,5632]  (gate tmp, then silu*up)
static const size_t WS_NEED  = 190840832;

// ---------------- async global->LDS 16B ----------------
__device__ __forceinline__ void glds16(const __bf16* g, __bf16* s) {
  __builtin_amdgcn_global_load_lds(
      (const __attribute__((address_space(1))) unsigned int*)(const void*)g,
      (__attribute__((address_space(3))) unsigned int*)(void*)s, 16, 0, 0);
}

// generic LDS pointer -> 32-bit LDS byte address (for asm ds_read)
__device__ __forceinline__ unsigned ldsa(const void* p) {
  return (unsigned)(unsigned long long)(__attribute__((address_space(3))) const char*)p;
}

// ---------------- fp32 -> bf16 convert ----------------
__global__ void cvt_kernel(const float* __restrict__ s, __bf16* __restrict__ d, int n4) {
  int i = blockIdx.x * 256 + threadIdx.x;
  if (i >= n4) return;
  float4 v = ((const float4*)s)[i];
  union { __bf16 b[4]; ushort4 u; } c;
  c.b[0] = (__bf16)v.x; c.b[1] = (__bf16)v.y; c.b[2] = (__bf16)v.z; c.b[3] = (__bf16)v.w;
  ((ushort4*)d)[i] = c.u;
}

// ---------------- RMSNorm (row of 2048, 256 threads) ----------------
__global__ __launch_bounds__(256)
void rmsnorm_kernel(const float* __restrict__ x, const float* __restrict__ w,
                    __bf16* __restrict__ out) {
  const int row = blockIdx.x, t = threadIdx.x;
  const float4* xr = (const float4*)(x + (size_t)row * DD);
  float4 a = xr[t], b = xr[t + 256];
  float s = a.x*a.x + a.y*a.y + a.z*a.z + a.w*a.w
          + b.x*b.x + b.y*b.y + b.z*b.z + b.w*b.w;
#pragma unroll
  for (int m = 1; m < 64; m <<= 1) s += __shfl_xor(s, m, 64);
  __shared__ float red[4];
  if ((t & 63) == 0) red[t >> 6] = s;
  __syncthreads();
  float tot = red[0] + red[1] + red[2] + red[3];
  float inv = 1.0f / (sqrtf(tot * (1.0f / 2048.0f) + 1e-6f) + 1e-6f);
  const float4* wr = (const float4*)w;
  float4 w0 = wr[t], w1 = wr[t + 256];
  __bf16* o = out + (size_t)row * DD;
  union { __bf16 bb[4]; ushort4 u; } c;
  c.bb[0] = (__bf16)(a.x*inv*w0.x); c.bb[1] = (__bf16)(a.y*inv*w0.y);
  c.bb[2] = (__bf16)(a.z*inv*w0.z); c.bb[3] = (__bf16)(a.w*inv*w0.w);
  ((ushort4*)o)[t] = c.u;
  c.bb[0] = (__bf16)(b.x*inv*w1.x); c.bb[1] = (__bf16)(b.y*inv*w1.y);
  c.bb[2] = (__bf16)(b.z*inv*w1.z); c.bb[3] = (__bf16)(b.w*inv*w1.w);
  ((ushort4*)o)[t + 256] = c.u;
}

// ---------------- NT GEMM 256x256: C[M,N] = A[M,K] * B[N,K]^T ----------------
// 8 waves (2Mx4N), per-wave 128x64 out. BK=64, 2 LDS tile-buffers (128 KiB).
// Chunks per operand per tile: 4 x (64 rows x 128B) = 1 glds16 each.
// Read schedule (tile kt, buf=kt&1): ph1 A{0,2}+B(kk0) ph2 A{1,3}(kk0)
//                                    ph3 A{0,2}+B(kk1) ph4 A{1,3}(kk1)
// Stage schedule: ph1 -> A1,A3 of kt+1 (nb; free)  [2]
//                 ph4 -> B0..3,A0,A2 of kt+2 (buf; dead since ph3) [6]
// Boundary: s_waitcnt vmcnt(6) (floats = 6 ph4-issued) + s_barrier.
// ds_read via volatile inline asm (no compiler LDS-DMA alias drains);
// lgkmcnt(0)+sched_barrier(0) before each 16-MFMA setprio cluster.
// EPI 0: Cb=(bf16)acc; EPI 1: Cf=Res+acc; EPI 2: Cb=(bf16)(silu(Cb)*acc)
template<int EPI>
__global__ __launch_bounds__(512, 2)
void gemm256_kernel(const __bf16* __restrict__ A, const __bf16* __restrict__ Bm,
                    __bf16* Cb, const float* __restrict__ Res,
                    float* __restrict__ Cf, int M, int N, int K) {
  __shared__ __align__(16) __bf16 LA[2][256 * 64];
  __shared__ __align__(16) __bf16 LB[2][256 * 64];
  const int t = threadIdx.x, w = t >> 6, l = t & 63;
  const int lm = l & 15, lq = l >> 4;
  const int wm = w & 1, wn = w >> 1;           // 2 x 4 wave grid
  const int NT = K >> 6;
  // bijective XCD swizzle (m204)
  const int nwg = gridDim.x * gridDim.y;
  const int lid = blockIdx.y * gridDim.x + blockIdx.x;
  const int q8 = nwg >> 3, r8 = nwg & 7;
  const int xcd = lid & 7, j0 = lid >> 3;
  const int wg = (xcd < r8 ? xcd * (q8 + 1) : r8 * (q8 + 1) + (xcd - r8) * q8) + j0;
  const int GN = N >> 8;
  const int m0 = (wg / GN) << 8, n0 = (wg % GN) << 8;

  // staging: chunk = 64 rows x 128B; thread -> row w*8+(l>>3), phys slot l&7,
  // global slot (l&7)^(row&7), row&7 == l>>3
  const int srow = l >> 3, sslot = (l & 7) ^ srow;
  const __bf16* Ag = A + (size_t)(m0 + w * 8 + srow) * K + sslot * 8;
  const __bf16* Bg = Bm + (size_t)(n0 + w * 8 + srow) * K + sslot * 8;
  const int dstoff = w * 512;                  // elements within chunk base

  // fragment read addresses (byte, LDS space); swizzled slot per kk
  const int sl0 = ((lq) ^ (lm & 7)) << 3;          // kk=0 (elements)
  const int sl1 = ((4 + lq) ^ (lm & 7)) << 3;      // kk=1
  const unsigned laB = ldsa(&LA[0][0]);
  const unsigned lbB = ldsa(&LB[0][0]);
  const unsigned aOff0 = ((wm * 128 + lm) * 64 + sl0) * 2;
  const unsigned aOff1 = ((wm * 128 + lm) * 64 + sl1) * 2;
  const unsigned bOff0 = ((wn * 64 + lm) * 64 + sl0) * 2;
  const unsigned bOff1 = ((wn * 64 + lm) * 64 + sl1) * 2;

  f32x4 acc[8][4] = {};
  bf16x8 aa[4], bb[4];

#define ST_A(bufi, kti, c) glds16(Ag + (size_t)((c) * 64) * K + (size_t)(kti) * 64, \
                                  &LA[bufi][(c) * 4096 + dstoff])
#define ST_B(bufi, kti, c) glds16(Bg + (size_t)((c) * 64) * K + (size_t)(kti) * 64, \
                                  &LB[bufi][(c) * 4096 + dstoff])
#define DSR(dst, addr, IMM) \
  asm volatile("ds_read_b128 %0, %1 offset:" #IMM : "=v"(dst) : "v"(addr))
#define WAITL() do { asm volatile("s_waitcnt lgkmcnt(0)" ::: "memory"); \
                     __builtin_amdgcn_sched_barrier(0); } while (0)
#define BAR() do { __builtin_amdgcn_s_barrier(); asm volatile("" ::: "memory"); } while (0)
#define CLUSTER16(I0)                                                              \
  __builtin_amdgcn_s_setprio(1);                                                   \
  _Pragma("unroll") for (int jj = 0; jj < 4; ++jj) {                               \
    acc[(I0) + 0][jj] = __builtin_amdgcn_mfma_f32_16x16x32_bf16(aa[0], bb[jj], acc[(I0) + 0][jj], 0, 0, 0); \
    acc[(I0) + 1][jj] = __builtin_amdgcn_mfma_f32_16x16x32_bf16(aa[1], bb[jj], acc[(I0) + 1][jj], 0, 0, 0); \
    acc[(I0) + 2][jj] = __builtin_amdgcn_mfma_f32_16x16x32_bf16(aa[2], bb[jj], acc[(I0) + 2][jj], 0, 0, 0); \
    acc[(I0) + 3][jj] = __builtin_amdgcn_mfma_f32_16x16x32_bf16(aa[3], bb[jj], acc[(I0) + 3][jj], 0, 0, 0); \
  }                                                                                \
  __builtin_amdgcn_s_setprio(0);

  // ---- prologue: tile0 full (8) + tile1 chunks B0-3,A0,A2 (6); NT >= 2 ----
  ST_B(0, 0, 0); ST_B(0, 0, 1); ST_B(0, 0, 2); ST_B(0, 0, 3);
  ST_A(0, 0, 0); ST_A(0, 0, 1); ST_A(0, 0, 2); ST_A(0, 0, 3);
  ST_B(1, 1, 0); ST_B(1, 1, 1); ST_B(1, 1, 2); ST_B(1, 1, 3);
  ST_A(1, 1, 0); ST_A(1, 1, 2);
  asm volatile("s_waitcnt vmcnt(6)" ::: "memory");
  __builtin_amdgcn_s_barrier();

  for (int kt = 0; kt < NT; ++kt) {
    const int buf = kt & 1, nb = buf ^ 1;
    const unsigned bufB = (unsigned)buf << 15;
    const unsigned aA0 = laB + bufB + aOff0, aA1 = laB + bufB + aOff1;
    const unsigned bB0 = lbB + bufB + bOff0, bB1 = lbB + bufB + bOff1;
    // ---- ph1: A{0,2} + B, kk0 ----
    DSR(aa[0], aA0, 0); DSR(aa[1], aA0, 2048); DSR(aa[2], aA0, 4096); DSR(aa[3], aA0, 6144);
    DSR(bb[0], bB0, 0); DSR(bb[1], bB0, 2048); DSR(bb[2], bB0, 4096); DSR(bb[3], bB0, 6144);
    if (kt + 1 < NT) { ST_A(nb, kt + 1, 1); ST_A(nb, kt + 1, 3); }   // finish tile kt+1
    BAR();
    WAITL();
    CLUSTER16(0);
    BAR();
    // ---- ph2: A{1,3}, kk0 (bb reused) ----
    DSR(aa[0], aA0, 8192); DSR(aa[1], aA0, 10240); DSR(aa[2], aA0, 12288); DSR(aa[3], aA0, 14336);
    BAR();
    WAITL();
    CLUSTER16(4);
    BAR();
    // ---- ph3: A{0,2} + B, kk1 ----
    DSR(aa[0], aA1, 0); DSR(aa[1], aA1, 2048); DSR(aa[2], aA1, 4096); DSR(aa[3], aA1, 6144);
    DSR(bb[0], bB1, 0); DSR(bb[1], bB1, 2048); DSR(bb[2], bB1, 4096); DSR(bb[3], bB1, 6144);
    BAR();
    WAITL();
    CLUSTER16(0);
    BAR();
    // ---- ph4: A{1,3}, kk1 ; stage 6 chunks of kt+2 into dead regions of buf ----
    DSR(aa[0], aA1, 8192); DSR(aa[1], aA1, 10240); DSR(aa[2], aA1, 12288); DSR(aa[3], aA1, 14336);
    if (kt + 2 < NT) {
      ST_B(buf, kt + 2, 0); ST_B(buf, kt + 2, 1); ST_B(buf, kt + 2, 2); ST_B(buf, kt + 2, 3);
      ST_A(buf, kt + 2, 0); ST_A(buf, kt + 2, 2);
    }
    BAR();
    WAITL();
    CLUSTER16(4);
    // ---- tile boundary: counted wait (own loads), then publish via barrier ----
    if (kt + 1 < NT) {
      if (kt + 2 < NT) asm volatile("s_waitcnt vmcnt(6)" ::: "memory");
      else             asm volatile("s_waitcnt vmcnt(0)" ::: "memory");
    }
    BAR();
  }

  // ---- epilogue ----
#pragma unroll
  for (int i = 0; i < 8; i++)
#pragma unroll
    for (int j = 0; j < 4; j++)
#pragma unroll
      for (int r = 0; r < 4; r++) {
        int row = m0 + wm * 128 + i * 16 + lq * 4 + r;
        int col = n0 + wn * 64 + j * 16 + lm;
        size_t idx = (size_t)row * N + col;
        if (EPI == 0) {
          Cb[idx] = (__bf16)acc[i][j][r];
        } else if (EPI == 1) {
          Cf[idx] = Res[idx] + acc[i][j][r];
        } else {
          float g = (float)Cb[idx];
          Cb[idx] = (__bf16)(g / (1.0f + __expf(-g)) * acc[i][j][r]);
        }
      }
#undef ST_A
#undef ST_B
#undef DSR
#undef WAITL
#undef BAR
#undef CLUSTER16
}

// ---------------- rope: out = rot_half(x) * (pm0+pm1) ----------------
__global__ __launch_bounds__(256)
void rope_kernel(const __bf16* __restrict__ qkv, const float* __restrict__ pm,
                 __bf16* __restrict__ qo, __bf16* __restrict__ ko) {
  const int row = blockIdx.x, t = threadIdx.x;
  const int s = row & 2047;
  const __bf16* q = qkv + (size_t)row * QKVN;
  const float* p0 = pm + (size_t)s * DD;
  const float* p1 = p0 + (size_t)2048 * DD;
  __bf16* qr = qo + (size_t)row * DD;
#pragma unroll
  for (int jj = 0; jj < 8; jj++) {
    int i = t + jj * 256;
    float rot = (i < 1024) ? -(float)q[i + 1024] : (float)q[i - 1024];
    qr[i] = (__bf16)(rot * (p0[i] + p1[i]));
  }
  const __bf16* k = q + 2048;
  __bf16* kr = ko + (size_t)row * KVD;
  {
    int i = t;
    float rot = (i < 128) ? -(float)k[i + 128] : (float)k[i - 128];
    kr[i] = (__bf16)(rot * (p0[i] + p1[i]));
  }
}

// ---------------- attention v2: transposed-S flash ----------------
// S^T = K·Q^T (C-layout: lane=q-col, rows=k_t) -> exp in-register is directly
// the A-fragment (k-permuted) of the PV 16x16x32 MFMA. No P through LDS.
// softmax = e/(sum e + 1): no max-rescale needed. grid (S/128, H, B).
__global__ __launch_bounds__(256)
void attn_kernel(const __bf16* __restrict__ Q, const __bf16* __restrict__ Kb,
                 const __bf16* __restrict__ QKV, __bf16* __restrict__ O) {
  __shared__ __align__(16) __bf16 sQ[128 * 72];
  __shared__ __align__(16) __bf16 sK[64 * 72];
  __shared__ __align__(16) __bf16 sV[64 * 72];   // [d][k] (V^T)
  __shared__ float sDen[128];
  const int t = threadIdx.x, l = t & 63, w = t >> 6;
  const int lm = l & 15, lq = l >> 4;
  const int q0 = blockIdx.x * 128;
  const int h = blockIdx.y, b = blockIdx.z;
  const int p = h & 3;                 // kv slice: head h uses dims p*64..p*64+64
  const float scale = 1.0f / (16.0f + 1e-6f);
  {
    const int qr = t >> 3, qc = (t & 7) * 8;
#pragma unroll
    for (int it = 0; it < 4; it++) {
      size_t base = ((size_t)(b * 2048 + q0 + qr + it * 32)) * DD + h * 64 + qc;
      *(uint4*)&sQ[(qr + it * 32) * 72 + qc] = *(const uint4*)(Q + base);
    }
  }
  f32x4 oacc[2][4] = {};                 // [q_j][d_n]
  float dsum[2] = {0.f, 0.f};            // per-lane partial denom, q = q_j*16+lm
  const int ksr = t >> 2, ksc = (t & 3) * 16;
  for (int kt = 0; kt < 2048; kt += 64) {
    const __bf16* krow = Kb + ((size_t)(b * 2048 + kt + ksr)) * KVD + p * 64 + ksc;
    uint4 kv0 = *(const uint4*)(krow);
    uint4 kv1 = *(const uint4*)(krow + 8);
    // V column-mode: lane = d (coalesced), wave w covers k = w*16..+15
    unsigned int vpack[8];
    {
      const __bf16* vbase = QKV + ((size_t)(b * 2048 + kt + w * 16)) * QKVN + 2304 + p * 64 + l;
#pragma unroll
      for (int j2 = 0; j2 < 8; j2++) {
        unsigned int u0 = *(const unsigned short*)(vbase + (size_t)(2 * j2) * QKVN);
        unsigned int u1 = *(const unsigned short*)(vbase + (size_t)(2 * j2 + 1) * QKVN);
        vpack[j2] = u0 | (u1 << 16);
      }
    }
    __syncthreads();
    *(uint4*)&sK[ksr * 72 + ksc] = kv0;
    *(uint4*)&sK[ksr * 72 + ksc + 8] = kv1;
    *(uint4*)&sV[l * 72 + w * 16] = *(uint4*)&vpack[0];
    *(uint4*)&sV[l * 72 + w * 16 + 8] = *(uint4*)&vpack[4];
    __syncthreads();
    // Q fragments (B-operand of S^T mfma), shared across kt chunks
    bf16x8 bQ[2][2];
#pragma unroll
    for (int q_j = 0; q_j < 2; q_j++)
#pragma unroll
      for (int kk = 0; kk < 2; kk++)
        bQ[q_j][kk] = *(const bf16x8*)&sQ[(w * 32 + q_j * 16 + lm) * 72 + kk * 32 + lq * 8];
#pragma unroll
    for (int kt2 = 0; kt2 < 2; kt2++) {  // pairs of 16-row k_t chunks
      union { bf16x8 v; __bf16 e[8]; } pA[2];
#pragma unroll
      for (int c = 0; c < 2; c++) {
        const int kt_i = kt2 * 2 + c;
        f32x4 sacc[2] = {};
#pragma unroll
        for (int kk = 0; kk < 2; kk++) {
          bf16x8 aK = *(const bf16x8*)&sK[(kt_i * 16 + lm) * 72 + kk * 32 + lq * 8];
#pragma unroll
          for (int q_j = 0; q_j < 2; q_j++)
            sacc[q_j] = __builtin_amdgcn_mfma_f32_16x16x32_bf16(aK, bQ[q_j][kk], sacc[q_j], 0, 0, 0);
        }
#pragma unroll
        for (int q_j = 0; q_j < 2; q_j++)
#pragma unroll
          for (int r = 0; r < 4; r++) {
            float e = __expf(sacc[q_j][r] * scale);
            dsum[q_j] += e;
            pA[q_j].e[c * 4 + r] = (__bf16)e;
          }
      }
      // PV: B-frag k-permuted to match pA: j 0..3 <- k=kt2*32+lq*4+j, j 4..7 <- +16
#pragma unroll
      for (int d_n = 0; d_n < 4; d_n++) {
        union { bf16x8 v; bf16x4 h[2]; } bV;
        const __bf16* vb = &sV[(d_n * 16 + lm) * 72 + kt2 * 32 + lq * 4];
        bV.h[0] = *(const bf16x4*)(vb);
        bV.h[1] = *(const bf16x4*)(vb + 16);
#pragma unroll
        for (int q_j = 0; q_j < 2; q_j++)
          oacc[q_j][d_n] = __builtin_amdgcn_mfma_f32_16x16x32_bf16(pA[q_j].v, bV.v, oacc[q_j][d_n], 0, 0, 0);
      }
    }
  }
  // denom: reduce over lq groups (lanes lm, lm+16, lm+32, lm+48 share q)
#pragma unroll
  for (int q_j = 0; q_j < 2; q_j++) {
    dsum[q_j] += __shfl_xor(dsum[q_j], 16, 64);
    dsum[q_j] += __shfl_xor(dsum[q_j], 32, 64);
  }
  if (l < 16) {
    sDen[w * 32 + l] = dsum[0];
    sDen[w * 32 + 16 + l] = dsum[1];
  }
  __syncthreads();
#pragma unroll
  for (int q_j = 0; q_j < 2; q_j++)
#pragma unroll
    for (int d_n = 0; d_n < 4; d_n++)
#pragma unroll
      for (int r = 0; r < 4; r++) {
        int rloc = w * 32 + q_j * 16 + lq * 4 + r;
        int row = q0 + rloc;
        int col = h * 64 + d_n * 16 + lm;
        O[((size_t)(b * 2048 + row)) * DD + col] = (__bf16)(oacc[q_j][d_n][r] / (sDen[rloc] + 1.0f));
      }
}

// ---------------------------------------------------------------------------
extern "C" void kernel_launch(void* const* d_in, const int* in_sizes, int n_in,
                              void* d_out, int out_size, void* d_ws, size_t ws_size,
                              hipStream_t stream) {
  if (ws_size < WS_NEED) return;

  const float* x    = (const float*)d_in[0];
  const float* pm   = (const float*)d_in[1];
  const float* w_na = (const float*)d_in[2];
  const float* w_nf = (const float*)d_in[3];
  const float* wq   = (const float*)d_in[4];
  const float* wk   = (const float*)d_in[5];
  const float* wv   = (const float*)d_in[6];
  const float* wo   = (const float*)d_in[7];
  const float* wg   = (const float*)d_in[8];
  const float* wu   = (const float*)d_in[9];
  const float* wd   = (const float*)d_in[10];

  char* ws = (char*)d_ws;
  __bf16* wqkv_b = (__bf16*)(ws + OFF_WQKV);
  __bf16* wo_b   = (__bf16*)(ws + OFF_WO);
  __bf16* wg_b   = (__bf16*)(ws + OFF_WG);
  __bf16* wu_b   = (__bf16*)(ws + OFF_WU);
  __bf16* wdn_b  = (__bf16*)(ws + OFF_WDN);
  __bf16* h_b    = (__bf16*)(ws + OFF_H);
  __bf16* qkv_b  = (__bf16*)(ws + OFF_QKV);
  __bf16* q_b    = (__bf16*)(ws + OFF_Q);
  __bf16* k_b    = (__bf16*)(ws + OFF_K);
  __bf16* act_b  = (__bf16*)(ws + OFF_ACT);
  float*  x1     = (float*)d_out;

  cvt_kernel<<<4096, 256, 0, stream>>>(wq, wqkv_b, 1048576);
  cvt_kernel<<<512, 256, 0, stream>>>(wk, wqkv_b + (size_t)2048 * 2048, 131072);
  cvt_kernel<<<512, 256, 0, stream>>>(wv, wqkv_b + (size_t)2304 * 2048, 131072);
  cvt_kernel<<<4096, 256, 0, stream>>>(wo, wo_b, 1048576);
  cvt_kernel<<<11264, 256, 0, stream>>>(wg, wg_b, 2883584);
  cvt_kernel<<<11264, 256, 0, stream>>>(wu, wu_b, 2883584);
  cvt_kernel<<<11264, 256, 0, stream>>>(wd, wdn_b, 2883584);

  // ---- attention sublayer ----
  rmsnorm_kernel<<<4096, 256, 0, stream>>>(x, w_na, h_b);
  gemm256_kernel<0><<<dim3(10, 16), 512, 0, stream>>>(h_b, wqkv_b, qkv_b, nullptr, nullptr,
                                                      RR, QKVN, DD);
  rope_kernel<<<4096, 256, 0, stream>>>(qkv_b, pm, q_b, k_b);
  attn_kernel<<<dim3(16, 32, 2), 256, 0, stream>>>(q_b, k_b, qkv_b, h_b);
  gemm256_kernel<1><<<dim3(8, 16), 512, 0, stream>>>(h_b, wo_b, nullptr, x, x1,
                                                     RR, DD, DD);
  // ---- feedforward sublayer ----
  rmsnorm_kernel<<<4096, 256, 0, stream>>>(x1, w_nf, q_b);
  gemm256_kernel<0><<<dim3(22, 16), 512, 0, stream>>>(q_b, wg_b, act_b, nullptr, nullptr,
                                                      RR, DFF, DD);
  gemm256_kernel<2><<<dim3(22, 16), 512, 0, stream>>>(q_b, wu_b, act_b, nullptr, nullptr,
                                                      RR, DFF, DD);
  gemm256_kernel<1><<<dim3(8, 16), 512, 0, stream>>>(act_b, wdn_b, nullptr, x1, x1,
                                                     RR, DD, DFF);
}

// Round 4
// 967.293 us; speedup vs baseline: 1.0948x; 1.0285x over previous
//
#include <hip/hip_runtime.h>

// ---------------------------------------------------------------------------
// TransformerBlock: B=2,S=2048,D=2048,H=32,HD=64,G=8,KV=256,DFF=5632
// fp32 in/out. R4: grid-quantization-aware GEMM deployment.
//  - NEW gemm_nt2: BM=128 x BN=256, BK=64, 8 waves (2Mx4N, 64x64/wave),
//    96 KiB dbuf LDS, XOR-swizzled staging (conflicts=0, measured R2),
//    C++ ds_reads + raw barriers + setprio, per-phase 3-glds interleave,
//    boundary vmcnt. Deployed where rounds quantize well:
//    gate/up 704 blk (2.75 rds, eff .92), down/wo 256 blk (exact 1 rd).
//  - qkv keeps the proven 128^2/BK=32 kernel (640 blk, multi-block/CU).
// Attention / rmsnorm / rope unchanged.
// ---------------------------------------------------------------------------

typedef __attribute__((ext_vector_type(8))) __bf16 bf16x8;
typedef __attribute__((ext_vector_type(4))) __bf16 bf16x4;
typedef __attribute__((ext_vector_type(4))) float f32x4;

#define RR 4096      // B*S rows
#define DD 2048
#define KVD 256
#define QKVN 2560    // 2048 q + 256 k + 256 v
#define DFF 5632

// ---------------- workspace layout (bytes) ----------------
static const size_t OFF_WQKV = 0;              // bf16 [2560,2048]
static const size_t OFF_WO   = 10485760;       // bf16 [2048,2048]
static const size_t OFF_WG   = 18874368;       // bf16 [5632,2048]
static const size_t OFF_WU   = 41943040;       // bf16 [5632,2048]
static const size_t OFF_WDN  = 65011712;       // bf16 [2048,5632]
static const size_t OFF_H    = 88080384;       // bf16 [4096,2048]  (h, then attn_out)
static const size_t OFF_QKV  = 104857600;      // bf16 [4096,2560]
static const size_t OFF_Q    = 125829120;      // bf16 [4096,2048]  (q_rope, then h2)
static const size_t OFF_K    = 142606336;      // bf16 [4096,256]
static const size_t OFF_ACT  = 144703488;      // bf16 [4096,5632]  (gate tmp, then silu*up)
static const size_t WS_NEED  = 190840832;

// ---------------- async global->LDS 16B ----------------
__device__ __forceinline__ void glds16(const __bf16* g, __bf16* s) {
  __builtin_amdgcn_global_load_lds(
      (const __attribute__((address_space(1))) unsigned int*)(const void*)g,
      (__attribute__((address_space(3))) unsigned int*)(void*)s, 16, 0, 0);
}

// ---------------- fp32 -> bf16 convert ----------------
__global__ void cvt_kernel(const float* __restrict__ s, __bf16* __restrict__ d, int n4) {
  int i = blockIdx.x * 256 + threadIdx.x;
  if (i >= n4) return;
  float4 v = ((const float4*)s)[i];
  union { __bf16 b[4]; ushort4 u; } c;
  c.b[0] = (__bf16)v.x; c.b[1] = (__bf16)v.y; c.b[2] = (__bf16)v.z; c.b[3] = (__bf16)v.w;
  ((ushort4*)d)[i] = c.u;
}

// ---------------- RMSNorm (row of 2048, 256 threads) ----------------
__global__ __launch_bounds__(256)
void rmsnorm_kernel(const float* __restrict__ x, const float* __restrict__ w,
                    __bf16* __restrict__ out) {
  const int row = blockIdx.x, t = threadIdx.x;
  const float4* xr = (const float4*)(x + (size_t)row * DD);
  float4 a = xr[t], b = xr[t + 256];
  float s = a.x*a.x + a.y*a.y + a.z*a.z + a.w*a.w
          + b.x*b.x + b.y*b.y + b.z*b.z + b.w*b.w;
#pragma unroll
  for (int m = 1; m < 64; m <<= 1) s += __shfl_xor(s, m, 64);
  __shared__ float red[4];
  if ((t & 63) == 0) red[t >> 6] = s;
  __syncthreads();
  float tot = red[0] + red[1] + red[2] + red[3];
  float inv = 1.0f / (sqrtf(tot * (1.0f / 2048.0f) + 1e-6f) + 1e-6f);
  const float4* wr = (const float4*)w;
  float4 w0 = wr[t], w1 = wr[t + 256];
  __bf16* o = out + (size_t)row * DD;
  union { __bf16 bb[4]; ushort4 u; } c;
  c.bb[0] = (__bf16)(a.x*inv*w0.x); c.bb[1] = (__bf16)(a.y*inv*w0.y);
  c.bb[2] = (__bf16)(a.z*inv*w0.z); c.bb[3] = (__bf16)(a.w*inv*w0.w);
  ((ushort4*)o)[t] = c.u;
  c.bb[0] = (__bf16)(b.x*inv*w1.x); c.bb[1] = (__bf16)(b.y*inv*w1.y);
  c.bb[2] = (__bf16)(b.z*inv*w1.z); c.bb[3] = (__bf16)(b.w*inv*w1.w);
  ((ushort4*)o)[t + 256] = c.u;
}

// ---------------- NT GEMM 128x128 (qkv): C = A[M,K] * B[N,K]^T ----------------
// R0-proven kernel: 128x128 tile, BK=32, glds16 staging, multi-block/CU.
template<int EPI>
__global__ __launch_bounds__(256)
void gemm_nt_kernel(const __bf16* __restrict__ A, const __bf16* __restrict__ Bm,
                    __bf16* Cb, const float* __restrict__ Res,
                    float* __restrict__ Cf, int M, int N, int K) {
  __shared__ __align__(16) __bf16 As[128 * 32];
  __shared__ __align__(16) __bf16 Bs[128 * 32];
  const int t = threadIdx.x;
  const int GM = M >> 7, GN = N >> 7;
  int m_t, n_t;
  if (GM == 32 && (GN & 3) == 0) {
    int lid = blockIdx.y * gridDim.x + blockIdx.x;
    int xcd = lid & 7, i = lid >> 3;
    int c = i >> 4, j = i & 15;
    m_t = xcd * 4 + (j & 3);
    n_t = c * 4 + (j >> 2);
  } else {
    m_t = blockIdx.y; n_t = blockIdx.x;
  }
  const int m0 = m_t * 128, n0 = n_t * 128;
  const int w = t >> 6, l = t & 63;
  const int wm = w & 1, wn = w >> 1;
  const int lm = l & 15, lq = l >> 4;
  const int slot = w * 64 + l;
  const int r0 = slot >> 2;
  const int a0 = slot & 3;
  const __bf16* Ap0 = A + (size_t)(m0 + r0) * K + a0 * 8;
  const __bf16* Ap1 = A + (size_t)(m0 + r0 + 64) * K + a0 * 8;
  const __bf16* Bp0 = Bm + (size_t)(n0 + r0) * K + a0 * 8;
  const __bf16* Bp1 = Bm + (size_t)(n0 + r0 + 64) * K + a0 * 8;
  __bf16* AsW0 = As + w * 512;
  __bf16* AsW1 = As + 2048 + w * 512;
  __bf16* BsW0 = Bs + w * 512;
  __bf16* BsW1 = Bs + 2048 + w * 512;
  f32x4 acc[4][4] = {};
  for (int kt = 0; kt < K; kt += 32) {
    __syncthreads();
    glds16(Ap0 + kt, AsW0);
    glds16(Ap1 + kt, AsW1);
    glds16(Bp0 + kt, BsW0);
    glds16(Bp1 + kt, BsW1);
    __syncthreads();
    bf16x8 af[4], bfr[4];
#pragma unroll
    for (int i = 0; i < 4; i++)
      af[i] = *(const bf16x8*)&As[(wm * 64 + i * 16 + lm) * 32 + lq * 8];
#pragma unroll
    for (int j = 0; j < 4; j++)
      bfr[j] = *(const bf16x8*)&Bs[(wn * 64 + j * 16 + lm) * 32 + lq * 8];
#pragma unroll
    for (int i = 0; i < 4; i++)
#pragma unroll
      for (int j = 0; j < 4; j++)
        acc[i][j] = __builtin_amdgcn_mfma_f32_16x16x32_bf16(af[i], bfr[j], acc[i][j], 0, 0, 0);
  }
#pragma unroll
  for (int i = 0; i < 4; i++)
#pragma unroll
    for (int j = 0; j < 4; j++)
#pragma unroll
      for (int r = 0; r < 4; r++) {
        int row = m0 + wm * 64 + i * 16 + lq * 4 + r;
        int col = n0 + wn * 64 + j * 16 + lm;
        size_t idx = (size_t)row * N + col;
        if (EPI == 0) {
          Cb[idx] = (__bf16)acc[i][j][r];
        } else if (EPI == 1) {
          Cf[idx] = Res[idx] + acc[i][j][r];
        } else {
          float g = (float)Cb[idx];
          Cb[idx] = (__bf16)(g / (1.0f + __expf(-g)) * acc[i][j][r]);
        }
      }
}

// ---------------- NT GEMM 128x256: C[M,N] = A[M,K] * B[N,K]^T ----------------
// 8 waves (2M x 4N), per-wave 64x64 out (acc 4x4). BK=64, dbuf LDS 96 KiB.
// Staging chunk = 64 rows x 128B = 1 glds16/512thr; A 2 chunks, B 4 chunks.
// Row-XOR slot swizzle (phys slot = logical ^ (row&7)); global source
// pre-swizzled (rule #21); fragment reads conflict-free (measured R2: 0).
// 2 phases/K-tile: {read 4A+4B frags kk, stage 3 chunks of kt+1, BAR,
// setprio 16-MFMA, BAR}; boundary vmcnt(0)+BAR.
// EPI 0: Cb=(bf16)acc; EPI 1: Cf=Res+acc; EPI 2: Cb=(bf16)(silu(Cb)*acc)
template<int EPI>
__global__ __launch_bounds__(512, 2)
void gemm_nt2_kernel(const __bf16* __restrict__ A, const __bf16* __restrict__ Bm,
                     __bf16* Cb, const float* __restrict__ Res,
                     float* __restrict__ Cf, int M, int N, int K) {
  __shared__ __align__(16) __bf16 LA[2][128 * 64];
  __shared__ __align__(16) __bf16 LB[2][256 * 64];
  const int t = threadIdx.x, w = t >> 6, l = t & 63;
  const int lm = l & 15, lq = l >> 4;
  const int wm = w >> 2, wn = w & 3;           // 2M x 4N wave grid
  const int NT = K >> 6;
  // XCD swizzle (all nt2 grids have nwg % 8 == 0)
  const int nwg = gridDim.x * gridDim.y;
  const int lid = blockIdx.y * gridDim.x + blockIdx.x;
  const int q8 = nwg >> 3;
  const int wg = (lid & 7) * q8 + (lid >> 3);
  const int GN = N >> 8;
  const int m0 = (wg / GN) << 7, n0 = (wg % GN) << 8;

  // staging: chunk = 64 rows x 8 slots(16B); thread -> row w*8+(l>>3),
  // phys slot l&7, global slot (l&7)^(row&7) with row&7 == l>>3
  const int srow = l >> 3, sslot = (l & 7) ^ srow;
  const __bf16* Ag = A + (size_t)(m0 + w * 8 + srow) * K + sslot * 8;
  const __bf16* Bg = Bm + (size_t)(n0 + w * 8 + srow) * K + sslot * 8;
  const int dstoff = w * 512;                  // elements within chunk

  // fragment phys-slot (elements): (kk*4+lq) ^ (row&7), row&7 == lm&7
  const int sl0 = ((lq) ^ (lm & 7)) << 3;
  const int sl1 = ((4 + lq) ^ (lm & 7)) << 3;
  const int aRow = (wm * 64 + lm) * 64;
  const int bRow = (wn * 64 + lm) * 64;

  f32x4 acc[4][4] = {};
  bf16x8 af[4], bf[4];

#define ST_A(bufi, kti, c) glds16(Ag + (size_t)((c) * 64) * K + (size_t)(kti) * 64, \
                                  &LA[bufi][(c) * 4096 + dstoff])
#define ST_B(bufi, kti, c) glds16(Bg + (size_t)((c) * 64) * K + (size_t)(kti) * 64, \
                                  &LB[bufi][(c) * 4096 + dstoff])
#define BAR() do { __builtin_amdgcn_s_barrier(); asm volatile("" ::: "memory"); } while (0)
#define CLUSTER16()                                                                \
  __builtin_amdgcn_s_setprio(1);                                                   \
  _Pragma("unroll") for (int jj = 0; jj < 4; ++jj) {                               \
    acc[0][jj] = __builtin_amdgcn_mfma_f32_16x16x32_bf16(af[0], bf[jj], acc[0][jj], 0, 0, 0); \
    acc[1][jj] = __builtin_amdgcn_mfma_f32_16x16x32_bf16(af[1], bf[jj], acc[1][jj], 0, 0, 0); \
    acc[2][jj] = __builtin_amdgcn_mfma_f32_16x16x32_bf16(af[2], bf[jj], acc[2][jj], 0, 0, 0); \
    acc[3][jj] = __builtin_amdgcn_mfma_f32_16x16x32_bf16(af[3], bf[jj], acc[3][jj], 0, 0, 0); \
  }                                                                                \
  __builtin_amdgcn_s_setprio(0);

  // ---- prologue: stage tile 0 (A0,A1,B0..3) ----
  ST_A(0, 0, 0); ST_A(0, 0, 1);
  ST_B(0, 0, 0); ST_B(0, 0, 1); ST_B(0, 0, 2); ST_B(0, 0, 3);
  asm volatile("s_waitcnt vmcnt(0)" ::: "memory");
  __builtin_amdgcn_s_barrier();

  for (int kt = 0; kt < NT; ++kt) {
    const int buf = kt & 1, nb = buf ^ 1;
    // ---- ph1: kk0 ----
#pragma unroll
    for (int i = 0; i < 4; i++) af[i] = *(const bf16x8*)&LA[buf][aRow + i * 1024 + sl0];
#pragma unroll
    for (int j = 0; j < 4; j++) bf[j] = *(const bf16x8*)&LB[buf][bRow + j * 1024 + sl0];
    if (kt + 1 < NT) { ST_B(nb, kt + 1, 0); ST_B(nb, kt + 1, 1); ST_B(nb, kt + 1, 2); }
    BAR();
    CLUSTER16();
    BAR();
    // ---- ph2: kk1 ----
#pragma unroll
    for (int i = 0; i < 4; i++) af[i] = *(const bf16x8*)&LA[buf][aRow + i * 1024 + sl1];
#pragma unroll
    for (int j = 0; j < 4; j++) bf[j] = *(const bf16x8*)&LB[buf][bRow + j * 1024 + sl1];
    if (kt + 1 < NT) { ST_B(nb, kt + 1, 3); ST_A(nb, kt + 1, 0); ST_A(nb, kt + 1, 1); }
    BAR();
    CLUSTER16();
    // ---- boundary: next tile resident, publish ----
    if (kt + 1 < NT) asm volatile("s_waitcnt vmcnt(0)" ::: "memory");
    BAR();
  }

  // ---- epilogue ----
#pragma unroll
  for (int i = 0; i < 4; i++)
#pragma unroll
    for (int j = 0; j < 4; j++)
#pragma unroll
      for (int r = 0; r < 4; r++) {
        int row = m0 + wm * 64 + i * 16 + lq * 4 + r;
        int col = n0 + wn * 64 + j * 16 + lm;
        size_t idx = (size_t)row * N + col;
        if (EPI == 0) {
          Cb[idx] = (__bf16)acc[i][j][r];
        } else if (EPI == 1) {
          Cf[idx] = Res[idx] + acc[i][j][r];
        } else {
          float g = (float)Cb[idx];
          Cb[idx] = (__bf16)(g / (1.0f + __expf(-g)) * acc[i][j][r]);
        }
      }
#undef ST_A
#undef ST_B
#undef BAR
#undef CLUSTER16
}

// ---------------- rope: out = rot_half(x) * (pm0+pm1) ----------------
__global__ __launch_bounds__(256)
void rope_kernel(const __bf16* __restrict__ qkv, const float* __restrict__ pm,
                 __bf16* __restrict__ qo, __bf16* __restrict__ ko) {
  const int row = blockIdx.x, t = threadIdx.x;
  const int s = row & 2047;
  const __bf16* q = qkv + (size_t)row * QKVN;
  const float* p0 = pm + (size_t)s * DD;
  const float* p1 = p0 + (size_t)2048 * DD;
  __bf16* qr = qo + (size_t)row * DD;
#pragma unroll
  for (int jj = 0; jj < 8; jj++) {
    int i = t + jj * 256;
    float rot = (i < 1024) ? -(float)q[i + 1024] : (float)q[i - 1024];
    qr[i] = (__bf16)(rot * (p0[i] + p1[i]));
  }
  const __bf16* k = q + 2048;
  __bf16* kr = ko + (size_t)row * KVD;
  {
    int i = t;
    float rot = (i < 128) ? -(float)k[i + 128] : (float)k[i - 128];
    kr[i] = (__bf16)(rot * (p0[i] + p1[i]));
  }
}

// ---------------- attention v2: transposed-S flash ----------------
// S^T = K·Q^T (C-layout: lane=q-col, rows=k_t) -> exp in-register is directly
// the A-fragment (k-permuted) of the PV 16x16x32 MFMA. No P through LDS.
// softmax = e/(sum e + 1): no max-rescale needed. grid (S/128, H, B).
__global__ __launch_bounds__(256)
void attn_kernel(const __bf16* __restrict__ Q, const __bf16* __restrict__ Kb,
                 const __bf16* __restrict__ QKV, __bf16* __restrict__ O) {
  __shared__ __align__(16) __bf16 sQ[128 * 72];
  __shared__ __align__(16) __bf16 sK[64 * 72];
  __shared__ __align__(16) __bf16 sV[64 * 72];   // [d][k] (V^T)
  __shared__ float sDen[128];
  const int t = threadIdx.x, l = t & 63, w = t >> 6;
  const int lm = l & 15, lq = l >> 4;
  const int q0 = blockIdx.x * 128;
  const int h = blockIdx.y, b = blockIdx.z;
  const int p = h & 3;                 // kv slice: head h uses dims p*64..p*64+64
  const float scale = 1.0f / (16.0f + 1e-6f);
  {
    const int qr = t >> 3, qc = (t & 7) * 8;
#pragma unroll
    for (int it = 0; it < 4; it++) {
      size_t base = ((size_t)(b * 2048 + q0 + qr + it * 32)) * DD + h * 64 + qc;
      *(uint4*)&sQ[(qr + it * 32) * 72 + qc] = *(const uint4*)(Q + base);
    }
  }
  f32x4 oacc[2][4] = {};                 // [q_j][d_n]
  float dsum[2] = {0.f, 0.f};            // per-lane partial denom, q = q_j*16+lm
  const int ksr = t >> 2, ksc = (t & 3) * 16;
  for (int kt = 0; kt < 2048; kt += 64) {
    const __bf16* krow = Kb + ((size_t)(b * 2048 + kt + ksr)) * KVD + p * 64 + ksc;
    uint4 kv0 = *(const uint4*)(krow);
    uint4 kv1 = *(const uint4*)(krow + 8);
    // V column-mode: lane = d (coalesced), wave w covers k = w*16..+15
    unsigned int vpack[8];
    {
      const __bf16* vbase = QKV + ((size_t)(b * 2048 + kt + w * 16)) * QKVN + 2304 + p * 64 + l;
#pragma unroll
      for (int j2 = 0; j2 < 8; j2++) {
        unsigned int u0 = *(const unsigned short*)(vbase + (size_t)(2 * j2) * QKVN);
        unsigned int u1 = *(const unsigned short*)(vbase + (size_t)(2 * j2 + 1) * QKVN);
        vpack[j2] = u0 | (u1 << 16);
      }
    }
    __syncthreads();
    *(uint4*)&sK[ksr * 72 + ksc] = kv0;
    *(uint4*)&sK[ksr * 72 + ksc + 8] = kv1;
    *(uint4*)&sV[l * 72 + w * 16] = *(uint4*)&vpack[0];
    *(uint4*)&sV[l * 72 + w * 16 + 8] = *(uint4*)&vpack[4];
    __syncthreads();
    // Q fragments (B-operand of S^T mfma), shared across kt chunks
    bf16x8 bQ[2][2];
#pragma unroll
    for (int q_j = 0; q_j < 2; q_j++)
#pragma unroll
      for (int kk = 0; kk < 2; kk++)
        bQ[q_j][kk] = *(const bf16x8*)&sQ[(w * 32 + q_j * 16 + lm) * 72 + kk * 32 + lq * 8];
#pragma unroll
    for (int kt2 = 0; kt2 < 2; kt2++) {  // pairs of 16-row k_t chunks
      union { bf16x8 v; __bf16 e[8]; } pA[2];
#pragma unroll
      for (int c = 0; c < 2; c++) {
        const int kt_i = kt2 * 2 + c;
        f32x4 sacc[2] = {};
#pragma unroll
        for (int kk = 0; kk < 2; kk++) {
          bf16x8 aK = *(const bf16x8*)&sK[(kt_i * 16 + lm) * 72 + kk * 32 + lq * 8];
#pragma unroll
          for (int q_j = 0; q_j < 2; q_j++)
            sacc[q_j] = __builtin_amdgcn_mfma_f32_16x16x32_bf16(aK, bQ[q_j][kk], sacc[q_j], 0, 0, 0);
        }
#pragma unroll
        for (int q_j = 0; q_j < 2; q_j++)
#pragma unroll
          for (int r = 0; r < 4; r++) {
            float e = __expf(sacc[q_j][r] * scale);
            dsum[q_j] += e;
            pA[q_j].e[c * 4 + r] = (__bf16)e;
          }
      }
      // PV: B-frag k-permuted to match pA: j 0..3 <- k=kt2*32+lq*4+j, j 4..7 <- +16
#pragma unroll
      for (int d_n = 0; d_n < 4; d_n++) {
        union { bf16x8 v; bf16x4 h[2]; } bV;
        const __bf16* vb = &sV[(d_n * 16 + lm) * 72 + kt2 * 32 + lq * 4];
        bV.h[0] = *(const bf16x4*)(vb);
        bV.h[1] = *(const bf16x4*)(vb + 16);
#pragma unroll
        for (int q_j = 0; q_j < 2; q_j++)
          oacc[q_j][d_n] = __builtin_amdgcn_mfma_f32_16x16x32_bf16(pA[q_j].v, bV.v, oacc[q_j][d_n], 0, 0, 0);
      }
    }
  }
  // denom: reduce over lq groups (lanes lm, lm+16, lm+32, lm+48 share q)
#pragma unroll
  for (int q_j = 0; q_j < 2; q_j++) {
    dsum[q_j] += __shfl_xor(dsum[q_j], 16, 64);
    dsum[q_j] += __shfl_xor(dsum[q_j], 32, 64);
  }
  if (l < 16) {
    sDen[w * 32 + l] = dsum[0];
    sDen[w * 32 + 16 + l] = dsum[1];
  }
  __syncthreads();
#pragma unroll
  for (int q_j = 0; q_j < 2; q_j++)
#pragma unroll
    for (int d_n = 0; d_n < 4; d_n++)
#pragma unroll
      for (int r = 0; r < 4; r++) {
        int rloc = w * 32 + q_j * 16 + lq * 4 + r;
        int row = q0 + rloc;
        int col = h * 64 + d_n * 16 + lm;
        O[((size_t)(b * 2048 + row)) * DD + col] = (__bf16)(oacc[q_j][d_n][r] / (sDen[rloc] + 1.0f));
      }
}

// ---------------------------------------------------------------------------
extern "C" void kernel_launch(void* const* d_in, const int* in_sizes, int n_in,
                              void* d_out, int out_size, void* d_ws, size_t ws_size,
                              hipStream_t stream) {
  if (ws_size < WS_NEED) return;

  const float* x    = (const float*)d_in[0];
  const float* pm   = (const float*)d_in[1];
  const float* w_na = (const float*)d_in[2];
  const float* w_nf = (const float*)d_in[3];
  const float* wq   = (const float*)d_in[4];
  const float* wk   = (const float*)d_in[5];
  const float* wv   = (const float*)d_in[6];
  const float* wo   = (const float*)d_in[7];
  const float* wg   = (const float*)d_in[8];
  const float* wu   = (const float*)d_in[9];
  const float* wd   = (const float*)d_in[10];

  char* ws = (char*)d_ws;
  __bf16* wqkv_b = (__bf16*)(ws + OFF_WQKV);
  __bf16* wo_b   = (__bf16*)(ws + OFF_WO);
  __bf16* wg_b   = (__bf16*)(ws + OFF_WG);
  __bf16* wu_b   = (__bf16*)(ws + OFF_WU);
  __bf16* wdn_b  = (__bf16*)(ws + OFF_WDN);
  __bf16* h_b    = (__bf16*)(ws + OFF_H);
  __bf16* qkv_b  = (__bf16*)(ws + OFF_QKV);
  __bf16* q_b    = (__bf16*)(ws + OFF_Q);
  __bf16* k_b    = (__bf16*)(ws + OFF_K);
  __bf16* act_b  = (__bf16*)(ws + OFF_ACT);
  float*  x1     = (float*)d_out;

  cvt_kernel<<<4096, 256, 0, stream>>>(wq, wqkv_b, 1048576);
  cvt_kernel<<<512, 256, 0, stream>>>(wk, wqkv_b + (size_t)2048 * 2048, 131072);
  cvt_kernel<<<512, 256, 0, stream>>>(wv, wqkv_b + (size_t)2304 * 2048, 131072);
  cvt_kernel<<<4096, 256, 0, stream>>>(wo, wo_b, 1048576);
  cvt_kernel<<<11264, 256, 0, stream>>>(wg, wg_b, 2883584);
  cvt_kernel<<<11264, 256, 0, stream>>>(wu, wu_b, 2883584);
  cvt_kernel<<<11264, 256, 0, stream>>>(wd, wdn_b, 2883584);

  // ---- attention sublayer ----
  rmsnorm_kernel<<<4096, 256, 0, stream>>>(x, w_na, h_b);
  gemm_nt_kernel<0><<<dim3(20, 32), 256, 0, stream>>>(h_b, wqkv_b, qkv_b, nullptr, nullptr,
                                                      RR, QKVN, DD);
  rope_kernel<<<4096, 256, 0, stream>>>(qkv_b, pm, q_b, k_b);
  attn_kernel<<<dim3(16, 32, 2), 256, 0, stream>>>(q_b, k_b, qkv_b, h_b);
  gemm_nt2_kernel<1><<<dim3(8, 32), 512, 0, stream>>>(h_b, wo_b, nullptr, x, x1,
                                                      RR, DD, DD);
  // ---- feedforward sublayer ----
  rmsnorm_kernel<<<4096, 256, 0, stream>>>(x1, w_nf, q_b);
  gemm_nt2_kernel<0><<<dim3(22, 32), 512, 0, stream>>>(q_b, wg_b, act_b, nullptr, nullptr,
                                                       RR, DFF, DD);
  gemm_nt2_kernel<2><<<dim3(22, 32), 512, 0, stream>>>(q_b, wu_b, act_b, nullptr, nullptr,
                                                       RR, DFF, DD);
  gemm_nt2_kernel<1><<<dim3(8, 32), 512, 0, stream>>>(act_b, wdn_b, nullptr, x1, x1,
                                                      RR, DD, DFF);
}

// Round 5
// 894.930 us; speedup vs baseline: 1.1833x; 1.0809x over previous
//
#include <hip/hip_runtime.h>

// ---------------------------------------------------------------------------
// TransformerBlock: B=2,S=2048,D=2048,H=32,HD=64,G=8,KV=256,DFF=5632
// fp32 in/out. R5: all GEMMs on the m97-form 128x128/BK=64 kernel WITH the
// R2/R4-proven XOR slot swizzle (conflicts=0). Single-buffer LDS (32 KiB ->
// 4-5 blocks/CU co-resident; m114 implicit wave overlap), plain syncthreads
// pairs, 8 glds16 + 16 ds_read_b128 + 32 MFMA per K-tile per wave.
// Attention / rmsnorm / rope unchanged.
// ---------------------------------------------------------------------------

typedef __attribute__((ext_vector_type(8))) __bf16 bf16x8;
typedef __attribute__((ext_vector_type(4))) __bf16 bf16x4;
typedef __attribute__((ext_vector_type(4))) float f32x4;

#define RR 4096      // B*S rows
#define DD 2048
#define KVD 256
#define QKVN 2560    // 2048 q + 256 k + 256 v
#define DFF 5632

// ---------------- workspace layout (bytes) ----------------
static const size_t OFF_WQKV = 0;              // bf16 [2560,2048]
static const size_t OFF_WO   = 10485760;       // bf16 [2048,2048]
static const size_t OFF_WG   = 18874368;       // bf16 [5632,2048]
static const size_t OFF_WU   = 41943040;       // bf16 [5632,2048]
static const size_t OFF_WDN  = 65011712;       // bf16 [2048,5632]
static const size_t OFF_H    = 88080384;       // bf16 [4096,2048]  (h, then attn_out)
static const size_t OFF_QKV  = 104857600;      // bf16 [4096,2560]
static const size_t OFF_Q    = 125829120;      // bf16 [4096,2048]  (q_rope, then h2)
static const size_t OFF_K    = 142606336;      // bf16 [4096,256]
static const size_t OFF_ACT  = 144703488;      // bf16 [4096,5632]  (gate tmp, then silu*up)
static const size_t WS_NEED  = 190840832;

// ---------------- async global->LDS 16B ----------------
__device__ __forceinline__ void glds16(const __bf16* g, __bf16* s) {
  __builtin_amdgcn_global_load_lds(
      (const __attribute__((address_space(1))) unsigned int*)(const void*)g,
      (__attribute__((address_space(3))) unsigned int*)(void*)s, 16, 0, 0);
}

// ---------------- fp32 -> bf16 convert ----------------
__global__ void cvt_kernel(const float* __restrict__ s, __bf16* __restrict__ d, int n4) {
  int i = blockIdx.x * 256 + threadIdx.x;
  if (i >= n4) return;
  float4 v = ((const float4*)s)[i];
  union { __bf16 b[4]; ushort4 u; } c;
  c.b[0] = (__bf16)v.x; c.b[1] = (__bf16)v.y; c.b[2] = (__bf16)v.z; c.b[3] = (__bf16)v.w;
  ((ushort4*)d)[i] = c.u;
}

// ---------------- RMSNorm (row of 2048, 256 threads) ----------------
__global__ __launch_bounds__(256)
void rmsnorm_kernel(const float* __restrict__ x, const float* __restrict__ w,
                    __bf16* __restrict__ out) {
  const int row = blockIdx.x, t = threadIdx.x;
  const float4* xr = (const float4*)(x + (size_t)row * DD);
  float4 a = xr[t], b = xr[t + 256];
  float s = a.x*a.x + a.y*a.y + a.z*a.z + a.w*a.w
          + b.x*b.x + b.y*b.y + b.z*b.z + b.w*b.w;
#pragma unroll
  for (int m = 1; m < 64; m <<= 1) s += __shfl_xor(s, m, 64);
  __shared__ float red[4];
  if ((t & 63) == 0) red[t >> 6] = s;
  __syncthreads();
  float tot = red[0] + red[1] + red[2] + red[3];
  float inv = 1.0f / (sqrtf(tot * (1.0f / 2048.0f) + 1e-6f) + 1e-6f);
  const float4* wr = (const float4*)w;
  float4 w0 = wr[t], w1 = wr[t + 256];
  __bf16* o = out + (size_t)row * DD;
  union { __bf16 bb[4]; ushort4 u; } c;
  c.bb[0] = (__bf16)(a.x*inv*w0.x); c.bb[1] = (__bf16)(a.y*inv*w0.y);
  c.bb[2] = (__bf16)(a.z*inv*w0.z); c.bb[3] = (__bf16)(a.w*inv*w0.w);
  ((ushort4*)o)[t] = c.u;
  c.bb[0] = (__bf16)(b.x*inv*w1.x); c.bb[1] = (__bf16)(b.y*inv*w1.y);
  c.bb[2] = (__bf16)(b.z*inv*w1.z); c.bb[3] = (__bf16)(b.w*inv*w1.w);
  ((ushort4*)o)[t + 256] = c.u;
}

// ---------------- NT GEMM: C[M,N] = A[M,K] * B[N,K]^T ----------------
// m97 form + XOR swizzle. 128x128 tile, BK=64, 256 thr (4 waves 2x2, 64x64
// each, acc 4x4). LDS 2 x 16 KiB single-buffered. Per K-tile: sync, 8 glds16,
// sync, 16 ds_read_b128, 32 MFMA.
// Swizzle (proven 0-conflict in R2/R4): rows are 8 x 16B slots; LDS phys slot
// s holds global slot s ^ (row&7). Staging: thread covers row it*32+w*8+(l>>3),
// phys slot l&7 -> global slot (l&7)^(l>>3). Reads: logical slot kk*4+lq at
// row with row&7==lm&7 -> phys ((kk*4+lq)^(lm&7)).
// Block swizzle: XCD (lid&7) owns m-band; n walked in 4-strip chunks (L2-hot).
// EPI 0: Cb=(bf16)acc; EPI 1: Cf=Res+acc; EPI 2: Cb=(bf16)(silu(Cb)*acc)
template<int EPI>
__global__ __launch_bounds__(256)
void gemm_nt_kernel(const __bf16* __restrict__ A, const __bf16* __restrict__ Bm,
                    __bf16* Cb, const float* __restrict__ Res,
                    float* __restrict__ Cf, int M, int N, int K) {
  __shared__ __align__(16) __bf16 As[128 * 64];
  __shared__ __align__(16) __bf16 Bs[128 * 64];
  const int t = threadIdx.x;
  const int GM = M >> 7, GN = N >> 7;
  int m_t, n_t;
  if (GM == 32 && (GN & 3) == 0) {
    int lid = blockIdx.y * gridDim.x + blockIdx.x;
    int xcd = lid & 7, i = lid >> 3;
    int c = i >> 4, j = i & 15;
    m_t = xcd * 4 + (j & 3);
    n_t = c * 4 + (j >> 2);
  } else {
    m_t = blockIdx.y; n_t = blockIdx.x;
  }
  const int m0 = m_t * 128, n0 = n_t * 128;
  const int w = t >> 6, l = t & 63;
  const int wm = w & 1, wn = w >> 1;
  const int lm = l & 15, lq = l >> 4;
  // staging: per issue 'it', 256 threads cover 32 rows x 128B.
  // thread row = it*32 + w*8 + (l>>3); LDS phys slot = l&7 (linear DMA dest);
  // global slot = (l&7) ^ (l>>3)  (row&7 == l>>3, invariant in 'it').
  const int srow = w * 8 + (l >> 3);
  const int sslot = (l & 7) ^ (l >> 3);
  const __bf16* Ap = A + (size_t)(m0 + srow) * K + sslot * 8;
  const __bf16* Bp = Bm + (size_t)(n0 + srow) * K + sslot * 8;
  __bf16* AsW = As + w * 512;    // wave-uniform LDS base (elements)
  __bf16* BsW = Bs + w * 512;
  // fragment phys-slot byte... element offsets: (kk*4+lq) ^ (lm&7)
  const int sl0 = ((lq) ^ (lm & 7)) << 3;
  const int sl1 = ((4 + lq) ^ (lm & 7)) << 3;
  f32x4 acc[4][4] = {};
  for (int kt = 0; kt < K; kt += 64) {
    __syncthreads();
#pragma unroll
    for (int it = 0; it < 4; it++) {
      glds16(Ap + (size_t)(it * 32) * K + kt, AsW + it * 2048);
      glds16(Bp + (size_t)(it * 32) * K + kt, BsW + it * 2048);
    }
    __syncthreads();
    bf16x8 af[2][4], bfr[2][4];
#pragma unroll
    for (int i = 0; i < 4; i++) {
      af[0][i]  = *(const bf16x8*)&As[(wm * 64 + i * 16 + lm) * 64 + sl0];
      af[1][i]  = *(const bf16x8*)&As[(wm * 64 + i * 16 + lm) * 64 + sl1];
      bfr[0][i] = *(const bf16x8*)&Bs[(wn * 64 + i * 16 + lm) * 64 + sl0];
      bfr[1][i] = *(const bf16x8*)&Bs[(wn * 64 + i * 16 + lm) * 64 + sl1];
    }
#pragma unroll
    for (int kk = 0; kk < 2; kk++)
#pragma unroll
      for (int i = 0; i < 4; i++)
#pragma unroll
        for (int j = 0; j < 4; j++)
          acc[i][j] = __builtin_amdgcn_mfma_f32_16x16x32_bf16(af[kk][i], bfr[kk][j], acc[i][j], 0, 0, 0);
  }
#pragma unroll
  for (int i = 0; i < 4; i++)
#pragma unroll
    for (int j = 0; j < 4; j++)
#pragma unroll
      for (int r = 0; r < 4; r++) {
        int row = m0 + wm * 64 + i * 16 + lq * 4 + r;
        int col = n0 + wn * 64 + j * 16 + lm;
        size_t idx = (size_t)row * N + col;
        if (EPI == 0) {
          Cb[idx] = (__bf16)acc[i][j][r];
        } else if (EPI == 1) {
          Cf[idx] = Res[idx] + acc[i][j][r];
        } else {
          float g = (float)Cb[idx];
          Cb[idx] = (__bf16)(g / (1.0f + __expf(-g)) * acc[i][j][r]);
        }
      }
}

// ---------------- rope: out = rot_half(x) * (pm0+pm1) ----------------
__global__ __launch_bounds__(256)
void rope_kernel(const __bf16* __restrict__ qkv, const float* __restrict__ pm,
                 __bf16* __restrict__ qo, __bf16* __restrict__ ko) {
  const int row = blockIdx.x, t = threadIdx.x;
  const int s = row & 2047;
  const __bf16* q = qkv + (size_t)row * QKVN;
  const float* p0 = pm + (size_t)s * DD;
  const float* p1 = p0 + (size_t)2048 * DD;
  __bf16* qr = qo + (size_t)row * DD;
#pragma unroll
  for (int jj = 0; jj < 8; jj++) {
    int i = t + jj * 256;
    float rot = (i < 1024) ? -(float)q[i + 1024] : (float)q[i - 1024];
    qr[i] = (__bf16)(rot * (p0[i] + p1[i]));
  }
  const __bf16* k = q + 2048;
  __bf16* kr = ko + (size_t)row * KVD;
  {
    int i = t;
    float rot = (i < 128) ? -(float)k[i + 128] : (float)k[i - 128];
    kr[i] = (__bf16)(rot * (p0[i] + p1[i]));
  }
}

// ---------------- attention v2: transposed-S flash ----------------
// S^T = K·Q^T (C-layout: lane=q-col, rows=k_t) -> exp in-register is directly
// the A-fragment (k-permuted) of the PV 16x16x32 MFMA. No P through LDS.
// softmax = e/(sum e + 1): no max-rescale needed. grid (S/128, H, B).
__global__ __launch_bounds__(256)
void attn_kernel(const __bf16* __restrict__ Q, const __bf16* __restrict__ Kb,
                 const __bf16* __restrict__ QKV, __bf16* __restrict__ O) {
  __shared__ __align__(16) __bf16 sQ[128 * 72];
  __shared__ __align__(16) __bf16 sK[64 * 72];
  __shared__ __align__(16) __bf16 sV[64 * 72];   // [d][k] (V^T)
  __shared__ float sDen[128];
  const int t = threadIdx.x, l = t & 63, w = t >> 6;
  const int lm = l & 15, lq = l >> 4;
  const int q0 = blockIdx.x * 128;
  const int h = blockIdx.y, b = blockIdx.z;
  const int p = h & 3;                 // kv slice: head h uses dims p*64..p*64+64
  const float scale = 1.0f / (16.0f + 1e-6f);
  {
    const int qr = t >> 3, qc = (t & 7) * 8;
#pragma unroll
    for (int it = 0; it < 4; it++) {
      size_t base = ((size_t)(b * 2048 + q0 + qr + it * 32)) * DD + h * 64 + qc;
      *(uint4*)&sQ[(qr + it * 32) * 72 + qc] = *(const uint4*)(Q + base);
    }
  }
  f32x4 oacc[2][4] = {};                 // [q_j][d_n]
  float dsum[2] = {0.f, 0.f};            // per-lane partial denom, q = q_j*16+lm
  const int ksr = t >> 2, ksc = (t & 3) * 16;
  for (int kt = 0; kt < 2048; kt += 64) {
    const __bf16* krow = Kb + ((size_t)(b * 2048 + kt + ksr)) * KVD + p * 64 + ksc;
    uint4 kv0 = *(const uint4*)(krow);
    uint4 kv1 = *(const uint4*)(krow + 8);
    // V column-mode: lane = d (coalesced), wave w covers k = w*16..+15
    unsigned int vpack[8];
    {
      const __bf16* vbase = QKV + ((size_t)(b * 2048 + kt + w * 16)) * QKVN + 2304 + p * 64 + l;
#pragma unroll
      for (int j2 = 0; j2 < 8; j2++) {
        unsigned int u0 = *(const unsigned short*)(vbase + (size_t)(2 * j2) * QKVN);
        unsigned int u1 = *(const unsigned short*)(vbase + (size_t)(2 * j2 + 1) * QKVN);
        vpack[j2] = u0 | (u1 << 16);
      }
    }
    __syncthreads();
    *(uint4*)&sK[ksr * 72 + ksc] = kv0;
    *(uint4*)&sK[ksr * 72 + ksc + 8] = kv1;
    *(uint4*)&sV[l * 72 + w * 16] = *(uint4*)&vpack[0];
    *(uint4*)&sV[l * 72 + w * 16 + 8] = *(uint4*)&vpack[4];
    __syncthreads();
    // Q fragments (B-operand of S^T mfma), shared across kt chunks
    bf16x8 bQ[2][2];
#pragma unroll
    for (int q_j = 0; q_j < 2; q_j++)
#pragma unroll
      for (int kk = 0; kk < 2; kk++)
        bQ[q_j][kk] = *(const bf16x8*)&sQ[(w * 32 + q_j * 16 + lm) * 72 + kk * 32 + lq * 8];
#pragma unroll
    for (int kt2 = 0; kt2 < 2; kt2++) {  // pairs of 16-row k_t chunks
      union { bf16x8 v; __bf16 e[8]; } pA[2];
#pragma unroll
      for (int c = 0; c < 2; c++) {
        const int kt_i = kt2 * 2 + c;
        f32x4 sacc[2] = {};
#pragma unroll
        for (int kk = 0; kk < 2; kk++) {
          bf16x8 aK = *(const bf16x8*)&sK[(kt_i * 16 + lm) * 72 + kk * 32 + lq * 8];
#pragma unroll
          for (int q_j = 0; q_j < 2; q_j++)
            sacc[q_j] = __builtin_amdgcn_mfma_f32_16x16x32_bf16(aK, bQ[q_j][kk], sacc[q_j], 0, 0, 0);
        }
#pragma unroll
        for (int q_j = 0; q_j < 2; q_j++)
#pragma unroll
          for (int r = 0; r < 4; r++) {
            float e = __expf(sacc[q_j][r] * scale);
            dsum[q_j] += e;
            pA[q_j].e[c * 4 + r] = (__bf16)e;
          }
      }
      // PV: B-frag k-permuted to match pA: j 0..3 <- k=kt2*32+lq*4+j, j 4..7 <- +16
#pragma unroll
      for (int d_n = 0; d_n < 4; d_n++) {
        union { bf16x8 v; bf16x4 h[2]; } bV;
        const __bf16* vb = &sV[(d_n * 16 + lm) * 72 + kt2 * 32 + lq * 4];
        bV.h[0] = *(const bf16x4*)(vb);
        bV.h[1] = *(const bf16x4*)(vb + 16);
#pragma unroll
        for (int q_j = 0; q_j < 2; q_j++)
          oacc[q_j][d_n] = __builtin_amdgcn_mfma_f32_16x16x32_bf16(pA[q_j].v, bV.v, oacc[q_j][d_n], 0, 0, 0);
      }
    }
  }
  // denom: reduce over lq groups (lanes lm, lm+16, lm+32, lm+48 share q)
#pragma unroll
  for (int q_j = 0; q_j < 2; q_j++) {
    dsum[q_j] += __shfl_xor(dsum[q_j], 16, 64);
    dsum[q_j] += __shfl_xor(dsum[q_j], 32, 64);
  }
  if (l < 16) {
    sDen[w * 32 + l] = dsum[0];
    sDen[w * 32 + 16 + l] = dsum[1];
  }
  __syncthreads();
#pragma unroll
  for (int q_j = 0; q_j < 2; q_j++)
#pragma unroll
    for (int d_n = 0; d_n < 4; d_n++)
#pragma unroll
      for (int r = 0; r < 4; r++) {
        int rloc = w * 32 + q_j * 16 + lq * 4 + r;
        int row = q0 + rloc;
        int col = h * 64 + d_n * 16 + lm;
        O[((size_t)(b * 2048 + row)) * DD + col] = (__bf16)(oacc[q_j][d_n][r] / (sDen[rloc] + 1.0f));
      }
}

// ---------------------------------------------------------------------------
extern "C" void kernel_launch(void* const* d_in, const int* in_sizes, int n_in,
                              void* d_out, int out_size, void* d_ws, size_t ws_size,
                              hipStream_t stream) {
  if (ws_size < WS_NEED) return;

  const float* x    = (const float*)d_in[0];
  const float* pm   = (const float*)d_in[1];
  const float* w_na = (const float*)d_in[2];
  const float* w_nf = (const float*)d_in[3];
  const float* wq   = (const float*)d_in[4];
  const float* wk   = (const float*)d_in[5];
  const float* wv   = (const float*)d_in[6];
  const float* wo   = (const float*)d_in[7];
  const float* wg   = (const float*)d_in[8];
  const float* wu   = (const float*)d_in[9];
  const float* wd   = (const float*)d_in[10];

  char* ws = (char*)d_ws;
  __bf16* wqkv_b = (__bf16*)(ws + OFF_WQKV);
  __bf16* wo_b   = (__bf16*)(ws + OFF_WO);
  __bf16* wg_b   = (__bf16*)(ws + OFF_WG);
  __bf16* wu_b   = (__bf16*)(ws + OFF_WU);
  __bf16* wdn_b  = (__bf16*)(ws + OFF_WDN);
  __bf16* h_b    = (__bf16*)(ws + OFF_H);
  __bf16* qkv_b  = (__bf16*)(ws + OFF_QKV);
  __bf16* q_b    = (__bf16*)(ws + OFF_Q);
  __bf16* k_b    = (__bf16*)(ws + OFF_K);
  __bf16* act_b  = (__bf16*)(ws + OFF_ACT);
  float*  x1     = (float*)d_out;

  cvt_kernel<<<4096, 256, 0, stream>>>(wq, wqkv_b, 1048576);
  cvt_kernel<<<512, 256, 0, stream>>>(wk, wqkv_b + (size_t)2048 * 2048, 131072);
  cvt_kernel<<<512, 256, 0, stream>>>(wv, wqkv_b + (size_t)2304 * 2048, 131072);
  cvt_kernel<<<4096, 256, 0, stream>>>(wo, wo_b, 1048576);
  cvt_kernel<<<11264, 256, 0, stream>>>(wg, wg_b, 2883584);
  cvt_kernel<<<11264, 256, 0, stream>>>(wu, wu_b, 2883584);
  cvt_kernel<<<11264, 256, 0, stream>>>(wd, wdn_b, 2883584);

  // ---- attention sublayer ----
  rmsnorm_kernel<<<4096, 256, 0, stream>>>(x, w_na, h_b);
  gemm_nt_kernel<0><<<dim3(20, 32), 256, 0, stream>>>(h_b, wqkv_b, qkv_b, nullptr, nullptr,
                                                      RR, QKVN, DD);
  rope_kernel<<<4096, 256, 0, stream>>>(qkv_b, pm, q_b, k_b);
  attn_kernel<<<dim3(16, 32, 2), 256, 0, stream>>>(q_b, k_b, qkv_b, h_b);
  gemm_nt_kernel<1><<<dim3(16, 32), 256, 0, stream>>>(h_b, wo_b, nullptr, x, x1,
                                                      RR, DD, DD);
  // ---- feedforward sublayer ----
  rmsnorm_kernel<<<4096, 256, 0, stream>>>(x1, w_nf, q_b);
  gemm_nt_kernel<0><<<dim3(44, 32), 256, 0, stream>>>(q_b, wg_b, act_b, nullptr, nullptr,
                                                      RR, DFF, DD);
  gemm_nt_kernel<2><<<dim3(44, 32), 256, 0, stream>>>(q_b, wu_b, act_b, nullptr, nullptr,
                                                      RR, DFF, DD);
  gemm_nt_kernel<1><<<dim3(16, 32), 256, 0, stream>>>(act_b, wdn_b, nullptr, x1, x1,
                                                      RR, DD, DFF);
}

// Round 6
// 799.051 us; speedup vs baseline: 1.3253x; 1.1200x over previous
//
#include <hip/hip_runtime.h>

// ---------------------------------------------------------------------------
// TransformerBlock: B=2,S=2048,D=2048,H=32,HD=64,G=8,KV=256,DFF=5632
// fp32 in/out. R6: FFN gate+up fused into one GEMM (gemm_glu): A staged once,
// both products accumulated per-lane (acc_g + acc_u), silu(g)*u in-register
// epilogue -> kills one 158us pass + 92MB intermediate traffic. All GEMMs on
// the R5-proven m97-form BK=64 + XOR swizzle (conflicts=0). cvt collapsed to
// one range-partitioned kernel. Attention / rmsnorm / rope unchanged.
// ---------------------------------------------------------------------------

typedef __attribute__((ext_vector_type(8))) __bf16 bf16x8;
typedef __attribute__((ext_vector_type(4))) __bf16 bf16x4;
typedef __attribute__((ext_vector_type(4))) float f32x4;

#define RR 4096      // B*S rows
#define DD 2048
#define KVD 256
#define QKVN 2560    // 2048 q + 256 k + 256 v
#define DFF 5632

// ---------------- workspace layout (bytes) ----------------
static const size_t OFF_WQKV = 0;              // bf16 [2560,2048]
static const size_t OFF_WO   = 10485760;       // bf16 [2048,2048]
static const size_t OFF_WG   = 18874368;       // bf16 [5632,2048]
static const size_t OFF_WU   = 41943040;       // bf16 [5632,2048]
static const size_t OFF_WDN  = 65011712;       // bf16 [2048,5632]
static const size_t OFF_H    = 88080384;       // bf16 [4096,2048]  (h, then attn_out)
static const size_t OFF_QKV  = 104857600;      // bf16 [4096,2560]
static const size_t OFF_Q    = 125829120;      // bf16 [4096,2048]  (q_rope, then h2)
static const size_t OFF_K    = 142606336;      // bf16 [4096,256]
static const size_t OFF_ACT  = 144703488;      // bf16 [4096,5632]  (silu*up)
static const size_t WS_NEED  = 190840832;

// ---------------- async global->LDS 16B ----------------
__device__ __forceinline__ void glds16(const __bf16* g, __bf16* s) {
  __builtin_amdgcn_global_load_lds(
      (const __attribute__((address_space(1))) unsigned int*)(const void*)g,
      (__attribute__((address_space(3))) unsigned int*)(void*)s, 16, 0, 0);
}

// ---------------- fp32 -> bf16 convert, all weights in one launch ----------
// float4-index ranges: wq[0,1048576) wk[..1179648) wv[..1310720)
// wo[..2359296) wg[..5242880) wu[..8126464) wd[..11010048).
// wq/wk/wv write contiguously into wqkv (dst index = global i).
__global__ __launch_bounds__(256)
void cvt_all_kernel(const float* __restrict__ wq, const float* __restrict__ wk,
                    const float* __restrict__ wv, const float* __restrict__ wo,
                    const float* __restrict__ wg, const float* __restrict__ wu,
                    const float* __restrict__ wd, __bf16* __restrict__ wqkv,
                    __bf16* __restrict__ wob, __bf16* __restrict__ wgb,
                    __bf16* __restrict__ wub, __bf16* __restrict__ wdb) {
  int i = blockIdx.x * 256 + threadIdx.x;
  const float* s; __bf16* d; int si, di;
  if (i < 1048576)      { s = wq; d = wqkv; si = i;           di = i; }
  else if (i < 1179648) { s = wk; d = wqkv; si = i - 1048576; di = i; }
  else if (i < 1310720) { s = wv; d = wqkv; si = i - 1179648; di = i; }
  else if (i < 2359296) { s = wo; d = wob;  si = i - 1310720; di = si; }
  else if (i < 5242880) { s = wg; d = wgb;  si = i - 2359296; di = si; }
  else if (i < 8126464) { s = wu; d = wub;  si = i - 5242880; di = si; }
  else                  { s = wd; d = wdb;  si = i - 8126464; di = si; }
  float4 v = ((const float4*)s)[si];
  union { __bf16 b[4]; ushort4 u; } c;
  c.b[0] = (__bf16)v.x; c.b[1] = (__bf16)v.y; c.b[2] = (__bf16)v.z; c.b[3] = (__bf16)v.w;
  ((ushort4*)d)[di] = c.u;
}

// ---------------- RMSNorm (row of 2048, 256 threads) ----------------
__global__ __launch_bounds__(256)
void rmsnorm_kernel(const float* __restrict__ x, const float* __restrict__ w,
                    __bf16* __restrict__ out) {
  const int row = blockIdx.x, t = threadIdx.x;
  const float4* xr = (const float4*)(x + (size_t)row * DD);
  float4 a = xr[t], b = xr[t + 256];
  float s = a.x*a.x + a.y*a.y + a.z*a.z + a.w*a.w
          + b.x*b.x + b.y*b.y + b.z*b.z + b.w*b.w;
#pragma unroll
  for (int m = 1; m < 64; m <<= 1) s += __shfl_xor(s, m, 64);
  __shared__ float red[4];
  if ((t & 63) == 0) red[t >> 6] = s;
  __syncthreads();
  float tot = red[0] + red[1] + red[2] + red[3];
  float inv = 1.0f / (sqrtf(tot * (1.0f / 2048.0f) + 1e-6f) + 1e-6f);
  const float4* wr = (const float4*)w;
  float4 w0 = wr[t], w1 = wr[t + 256];
  __bf16* o = out + (size_t)row * DD;
  union { __bf16 bb[4]; ushort4 u; } c;
  c.bb[0] = (__bf16)(a.x*inv*w0.x); c.bb[1] = (__bf16)(a.y*inv*w0.y);
  c.bb[2] = (__bf16)(a.z*inv*w0.z); c.bb[3] = (__bf16)(a.w*inv*w0.w);
  ((ushort4*)o)[t] = c.u;
  c.bb[0] = (__bf16)(b.x*inv*w1.x); c.bb[1] = (__bf16)(b.y*inv*w1.y);
  c.bb[2] = (__bf16)(b.z*inv*w1.z); c.bb[3] = (__bf16)(b.w*inv*w1.w);
  ((ushort4*)o)[t + 256] = c.u;
}

// ---------------- NT GEMM: C[M,N] = A[M,K] * B[N,K]^T ----------------
// R5-proven: 128x128 tile, BK=64, 256 thr, XOR slot swizzle (0 conflicts).
template<int EPI>
__global__ __launch_bounds__(256)
void gemm_nt_kernel(const __bf16* __restrict__ A, const __bf16* __restrict__ Bm,
                    __bf16* Cb, const float* __restrict__ Res,
                    float* __restrict__ Cf, int M, int N, int K) {
  __shared__ __align__(16) __bf16 As[128 * 64];
  __shared__ __align__(16) __bf16 Bs[128 * 64];
  const int t = threadIdx.x;
  const int GM = M >> 7, GN = N >> 7;
  int m_t, n_t;
  if (GM == 32 && (GN & 3) == 0) {
    int lid = blockIdx.y * gridDim.x + blockIdx.x;
    int xcd = lid & 7, i = lid >> 3;
    int c = i >> 4, j = i & 15;
    m_t = xcd * 4 + (j & 3);
    n_t = c * 4 + (j >> 2);
  } else {
    m_t = blockIdx.y; n_t = blockIdx.x;
  }
  const int m0 = m_t * 128, n0 = n_t * 128;
  const int w = t >> 6, l = t & 63;
  const int wm = w & 1, wn = w >> 1;
  const int lm = l & 15, lq = l >> 4;
  const int srow = w * 8 + (l >> 3);
  const int sslot = (l & 7) ^ (l >> 3);
  const __bf16* Ap = A + (size_t)(m0 + srow) * K + sslot * 8;
  const __bf16* Bp = Bm + (size_t)(n0 + srow) * K + sslot * 8;
  __bf16* AsW = As + w * 512;
  __bf16* BsW = Bs + w * 512;
  const int sl0 = ((lq) ^ (lm & 7)) << 3;
  const int sl1 = ((4 + lq) ^ (lm & 7)) << 3;
  f32x4 acc[4][4] = {};
  for (int kt = 0; kt < K; kt += 64) {
    __syncthreads();
#pragma unroll
    for (int it = 0; it < 4; it++) {
      glds16(Ap + (size_t)(it * 32) * K + kt, AsW + it * 2048);
      glds16(Bp + (size_t)(it * 32) * K + kt, BsW + it * 2048);
    }
    __syncthreads();
    bf16x8 af[2][4], bfr[2][4];
#pragma unroll
    for (int i = 0; i < 4; i++) {
      af[0][i]  = *(const bf16x8*)&As[(wm * 64 + i * 16 + lm) * 64 + sl0];
      af[1][i]  = *(const bf16x8*)&As[(wm * 64 + i * 16 + lm) * 64 + sl1];
      bfr[0][i] = *(const bf16x8*)&Bs[(wn * 64 + i * 16 + lm) * 64 + sl0];
      bfr[1][i] = *(const bf16x8*)&Bs[(wn * 64 + i * 16 + lm) * 64 + sl1];
    }
#pragma unroll
    for (int kk = 0; kk < 2; kk++)
#pragma unroll
      for (int i = 0; i < 4; i++)
#pragma unroll
        for (int j = 0; j < 4; j++)
          acc[i][j] = __builtin_amdgcn_mfma_f32_16x16x32_bf16(af[kk][i], bfr[kk][j], acc[i][j], 0, 0, 0);
  }
#pragma unroll
  for (int i = 0; i < 4; i++)
#pragma unroll
    for (int j = 0; j < 4; j++)
#pragma unroll
      for (int r = 0; r < 4; r++) {
        int row = m0 + wm * 64 + i * 16 + lq * 4 + r;
        int col = n0 + wn * 64 + j * 16 + lm;
        size_t idx = (size_t)row * N + col;
        if (EPI == 0) {
          Cb[idx] = (__bf16)acc[i][j][r];
        } else {
          Cf[idx] = Res[idx] + acc[i][j][r];
        }
      }
}

// ---------------- fused SwiGLU GEMM: act = silu(A*G^T) * (A*U^T) ----------
// 512 thr (8 waves, 2M x 4N), wave computes 64x32 of BOTH gate and up
// (acc_g[4][2] + acc_u[4][2] = 64 VGPR). A staged ONCE for both products:
// per K-tile 6 glds16 (A,G,U x 2 chunks of 64 rows), 48 KiB LDS. Same XOR
// slot swizzle as gemm_nt (R5-proven 0-conflict). In-register silu(g)*u
// epilogue -> no gate intermediate.
__global__ __launch_bounds__(512)
void gemm_glu_kernel(const __bf16* __restrict__ A, const __bf16* __restrict__ Gm,
                     const __bf16* __restrict__ Um, __bf16* __restrict__ Cb,
                     int M, int N, int K) {
  __shared__ __align__(16) __bf16 As[128 * 64];
  __shared__ __align__(16) __bf16 Gs[128 * 64];
  __shared__ __align__(16) __bf16 Us[128 * 64];
  const int t = threadIdx.x, w = t >> 6, l = t & 63;
  const int lm = l & 15, lq = l >> 4;
  const int wm = w >> 2, wn = w & 3;           // 2M x 4N wave grid
  // XCD/L2 block swizzle (GM=32, GN=44; 1408 % 8 == 0 -> bijective)
  const int lid = blockIdx.y * gridDim.x + blockIdx.x;
  const int xcd = lid & 7, i0 = lid >> 3;
  const int cc = i0 >> 4, jj0 = i0 & 15;
  const int m0 = (xcd * 4 + (jj0 & 3)) * 128;
  const int n0 = (cc * 4 + (jj0 >> 2)) * 128;
  // staging: 512 thr cover 64 rows x 128B per issue; row = w*8+(l>>3),
  // phys slot l&7, global slot (l&7)^(l>>3)  (row&7 == l>>3)
  const int srow = w * 8 + (l >> 3);
  const int sslot = (l & 7) ^ (l >> 3);
  const __bf16* Ap = A + (size_t)(m0 + srow) * K + sslot * 8;
  const __bf16* Gp = Gm + (size_t)(n0 + srow) * K + sslot * 8;
  const __bf16* Up = Um + (size_t)(n0 + srow) * K + sslot * 8;
  __bf16* AsW = As + w * 512;
  __bf16* GsW = Gs + w * 512;
  __bf16* UsW = Us + w * 512;
  const int sl0 = ((lq) ^ (lm & 7)) << 3;
  const int sl1 = ((4 + lq) ^ (lm & 7)) << 3;
  f32x4 accg[4][2] = {}, accu[4][2] = {};
  for (int kt = 0; kt < K; kt += 64) {
    __syncthreads();
    glds16(Ap + kt, AsW);
    glds16(Ap + (size_t)64 * K + kt, AsW + 4096);
    glds16(Gp + kt, GsW);
    glds16(Gp + (size_t)64 * K + kt, GsW + 4096);
    glds16(Up + kt, UsW);
    glds16(Up + (size_t)64 * K + kt, UsW + 4096);
    __syncthreads();
#pragma unroll
    for (int kk = 0; kk < 2; kk++) {
      const int sl = kk ? sl1 : sl0;
      bf16x8 af[4], bg[2], bu[2];
#pragma unroll
      for (int i = 0; i < 4; i++)
        af[i] = *(const bf16x8*)&As[(wm * 64 + i * 16 + lm) * 64 + sl];
#pragma unroll
      for (int j = 0; j < 2; j++) {
        bg[j] = *(const bf16x8*)&Gs[(wn * 32 + j * 16 + lm) * 64 + sl];
        bu[j] = *(const bf16x8*)&Us[(wn * 32 + j * 16 + lm) * 64 + sl];
      }
#pragma unroll
      for (int i = 0; i < 4; i++)
#pragma unroll
        for (int j = 0; j < 2; j++) {
          accg[i][j] = __builtin_amdgcn_mfma_f32_16x16x32_bf16(af[i], bg[j], accg[i][j], 0, 0, 0);
          accu[i][j] = __builtin_amdgcn_mfma_f32_16x16x32_bf16(af[i], bu[j], accu[i][j], 0, 0, 0);
        }
    }
  }
#pragma unroll
  for (int i = 0; i < 4; i++)
#pragma unroll
    for (int j = 0; j < 2; j++)
#pragma unroll
      for (int r = 0; r < 4; r++) {
        int row = m0 + wm * 64 + i * 16 + lq * 4 + r;
        int col = n0 + wn * 32 + j * 16 + lm;
        float g = accg[i][j][r];
        Cb[(size_t)row * N + col] = (__bf16)(g / (1.0f + __expf(-g)) * accu[i][j][r]);
      }
}

// ---------------- rope: out = rot_half(x) * (pm0+pm1) ----------------
__global__ __launch_bounds__(256)
void rope_kernel(const __bf16* __restrict__ qkv, const float* __restrict__ pm,
                 __bf16* __restrict__ qo, __bf16* __restrict__ ko) {
  const int row = blockIdx.x, t = threadIdx.x;
  const int s = row & 2047;
  const __bf16* q = qkv + (size_t)row * QKVN;
  const float* p0 = pm + (size_t)s * DD;
  const float* p1 = p0 + (size_t)2048 * DD;
  __bf16* qr = qo + (size_t)row * DD;
#pragma unroll
  for (int jj = 0; jj < 8; jj++) {
    int i = t + jj * 256;
    float rot = (i < 1024) ? -(float)q[i + 1024] : (float)q[i - 1024];
    qr[i] = (__bf16)(rot * (p0[i] + p1[i]));
  }
  const __bf16* k = q + 2048;
  __bf16* kr = ko + (size_t)row * KVD;
  {
    int i = t;
    float rot = (i < 128) ? -(float)k[i + 128] : (float)k[i - 128];
    kr[i] = (__bf16)(rot * (p0[i] + p1[i]));
  }
}

// ---------------- attention v2: transposed-S flash ----------------
__global__ __launch_bounds__(256)
void attn_kernel(const __bf16* __restrict__ Q, const __bf16* __restrict__ Kb,
                 const __bf16* __restrict__ QKV, __bf16* __restrict__ O) {
  __shared__ __align__(16) __bf16 sQ[128 * 72];
  __shared__ __align__(16) __bf16 sK[64 * 72];
  __shared__ __align__(16) __bf16 sV[64 * 72];   // [d][k] (V^T)
  __shared__ float sDen[128];
  const int t = threadIdx.x, l = t & 63, w = t >> 6;
  const int lm = l & 15, lq = l >> 4;
  const int q0 = blockIdx.x * 128;
  const int h = blockIdx.y, b = blockIdx.z;
  const int p = h & 3;                 // kv slice: head h uses dims p*64..p*64+64
  const float scale = 1.0f / (16.0f + 1e-6f);
  {
    const int qr = t >> 3, qc = (t & 7) * 8;
#pragma unroll
    for (int it = 0; it < 4; it++) {
      size_t base = ((size_t)(b * 2048 + q0 + qr + it * 32)) * DD + h * 64 + qc;
      *(uint4*)&sQ[(qr + it * 32) * 72 + qc] = *(const uint4*)(Q + base);
    }
  }
  f32x4 oacc[2][4] = {};                 // [q_j][d_n]
  float dsum[2] = {0.f, 0.f};            // per-lane partial denom, q = q_j*16+lm
  const int ksr = t >> 2, ksc = (t & 3) * 16;
  for (int kt = 0; kt < 2048; kt += 64) {
    const __bf16* krow = Kb + ((size_t)(b * 2048 + kt + ksr)) * KVD + p * 64 + ksc;
    uint4 kv0 = *(const uint4*)(krow);
    uint4 kv1 = *(const uint4*)(krow + 8);
    // V column-mode: lane = d (coalesced), wave w covers k = w*16..+15
    unsigned int vpack[8];
    {
      const __bf16* vbase = QKV + ((size_t)(b * 2048 + kt + w * 16)) * QKVN + 2304 + p * 64 + l;
#pragma unroll
      for (int j2 = 0; j2 < 8; j2++) {
        unsigned int u0 = *(const unsigned short*)(vbase + (size_t)(2 * j2) * QKVN);
        unsigned int u1 = *(const unsigned short*)(vbase + (size_t)(2 * j2 + 1) * QKVN);
        vpack[j2] = u0 | (u1 << 16);
      }
    }
    __syncthreads();
    *(uint4*)&sK[ksr * 72 + ksc] = kv0;
    *(uint4*)&sK[ksr * 72 + ksc + 8] = kv1;
    *(uint4*)&sV[l * 72 + w * 16] = *(uint4*)&vpack[0];
    *(uint4*)&sV[l * 72 + w * 16 + 8] = *(uint4*)&vpack[4];
    __syncthreads();
    // Q fragments (B-operand of S^T mfma), shared across kt chunks
    bf16x8 bQ[2][2];
#pragma unroll
    for (int q_j = 0; q_j < 2; q_j++)
#pragma unroll
      for (int kk = 0; kk < 2; kk++)
        bQ[q_j][kk] = *(const bf16x8*)&sQ[(w * 32 + q_j * 16 + lm) * 72 + kk * 32 + lq * 8];
#pragma unroll
    for (int kt2 = 0; kt2 < 2; kt2++) {  // pairs of 16-row k_t chunks
      union { bf16x8 v; __bf16 e[8]; } pA[2];
#pragma unroll
      for (int c = 0; c < 2; c++) {
        const int kt_i = kt2 * 2 + c;
        f32x4 sacc[2] = {};
#pragma unroll
        for (int kk = 0; kk < 2; kk++) {
          bf16x8 aK = *(const bf16x8*)&sK[(kt_i * 16 + lm) * 72 + kk * 32 + lq * 8];
#pragma unroll
          for (int q_j = 0; q_j < 2; q_j++)
            sacc[q_j] = __builtin_amdgcn_mfma_f32_16x16x32_bf16(aK, bQ[q_j][kk], sacc[q_j], 0, 0, 0);
        }
#pragma unroll
        for (int q_j = 0; q_j < 2; q_j++)
#pragma unroll
          for (int r = 0; r < 4; r++) {
            float e = __expf(sacc[q_j][r] * scale);
            dsum[q_j] += e;
            pA[q_j].e[c * 4 + r] = (__bf16)e;
          }
      }
      // PV: B-frag k-permuted to match pA: j 0..3 <- k=kt2*32+lq*4+j, j 4..7 <- +16
#pragma unroll
      for (int d_n = 0; d_n < 4; d_n++) {
        union { bf16x8 v; bf16x4 h[2]; } bV;
        const __bf16* vb = &sV[(d_n * 16 + lm) * 72 + kt2 * 32 + lq * 4];
        bV.h[0] = *(const bf16x4*)(vb);
        bV.h[1] = *(const bf16x4*)(vb + 16);
#pragma unroll
        for (int q_j = 0; q_j < 2; q_j++)
          oacc[q_j][d_n] = __builtin_amdgcn_mfma_f32_16x16x32_bf16(pA[q_j].v, bV.v, oacc[q_j][d_n], 0, 0, 0);
      }
    }
  }
  // denom: reduce over lq groups (lanes lm, lm+16, lm+32, lm+48 share q)
#pragma unroll
  for (int q_j = 0; q_j < 2; q_j++) {
    dsum[q_j] += __shfl_xor(dsum[q_j], 16, 64);
    dsum[q_j] += __shfl_xor(dsum[q_j], 32, 64);
  }
  if (l < 16) {
    sDen[w * 32 + l] = dsum[0];
    sDen[w * 32 + 16 + l] = dsum[1];
  }
  __syncthreads();
#pragma unroll
  for (int q_j = 0; q_j < 2; q_j++)
#pragma unroll
    for (int d_n = 0; d_n < 4; d_n++)
#pragma unroll
      for (int r = 0; r < 4; r++) {
        int rloc = w * 32 + q_j * 16 + lq * 4 + r;
        int row = q0 + rloc;
        int col = h * 64 + d_n * 16 + lm;
        O[((size_t)(b * 2048 + row)) * DD + col] = (__bf16)(oacc[q_j][d_n][r] / (sDen[rloc] + 1.0f));
      }
}

// ---------------------------------------------------------------------------
extern "C" void kernel_launch(void* const* d_in, const int* in_sizes, int n_in,
                              void* d_out, int out_size, void* d_ws, size_t ws_size,
                              hipStream_t stream) {
  if (ws_size < WS_NEED) return;

  const float* x    = (const float*)d_in[0];
  const float* pm   = (const float*)d_in[1];
  const float* w_na = (const float*)d_in[2];
  const float* w_nf = (const float*)d_in[3];
  const float* wq   = (const float*)d_in[4];
  const float* wk   = (const float*)d_in[5];
  const float* wv   = (const float*)d_in[6];
  const float* wo   = (const float*)d_in[7];
  const float* wg   = (const float*)d_in[8];
  const float* wu   = (const float*)d_in[9];
  const float* wd   = (const float*)d_in[10];

  char* ws = (char*)d_ws;
  __bf16* wqkv_b = (__bf16*)(ws + OFF_WQKV);
  __bf16* wo_b   = (__bf16*)(ws + OFF_WO);
  __bf16* wg_b   = (__bf16*)(ws + OFF_WG);
  __bf16* wu_b   = (__bf16*)(ws + OFF_WU);
  __bf16* wdn_b  = (__bf16*)(ws + OFF_WDN);
  __bf16* h_b    = (__bf16*)(ws + OFF_H);
  __bf16* qkv_b  = (__bf16*)(ws + OFF_QKV);
  __bf16* q_b    = (__bf16*)(ws + OFF_Q);
  __bf16* k_b    = (__bf16*)(ws + OFF_K);
  __bf16* act_b  = (__bf16*)(ws + OFF_ACT);
  float*  x1     = (float*)d_out;

  cvt_all_kernel<<<43008, 256, 0, stream>>>(wq, wk, wv, wo, wg, wu, wd,
                                            wqkv_b, wo_b, wg_b, wu_b, wdn_b);

  // ---- attention sublayer ----
  rmsnorm_kernel<<<4096, 256, 0, stream>>>(x, w_na, h_b);
  gemm_nt_kernel<0><<<dim3(20, 32), 256, 0, stream>>>(h_b, wqkv_b, qkv_b, nullptr, nullptr,
                                                      RR, QKVN, DD);
  rope_kernel<<<4096, 256, 0, stream>>>(qkv_b, pm, q_b, k_b);
  attn_kernel<<<dim3(16, 32, 2), 256, 0, stream>>>(q_b, k_b, qkv_b, h_b);
  gemm_nt_kernel<1><<<dim3(16, 32), 256, 0, stream>>>(h_b, wo_b, nullptr, x, x1,
                                                      RR, DD, DD);
  // ---- feedforward sublayer ----
  rmsnorm_kernel<<<4096, 256, 0, stream>>>(x1, w_nf, q_b);
  gemm_glu_kernel<<<dim3(44, 32), 512, 0, stream>>>(q_b, wg_b, wu_b, act_b,
                                                    RR, DFF, DD);
  gemm_nt_kernel<1><<<dim3(16, 32), 256, 0, stream>>>(act_b, wdn_b, nullptr, x1, x1,
                                                      RR, DD, DFF);
}